// Round 7
// baseline (5990.696 us; speedup 1.0000x reference)
//
#include <hip/hip_runtime.h>
#include <math.h>

#define BATCH 8
#define SEQ   2048
#define IN    8
#define HID   256
#define G4    1024   // 4*HID

typedef unsigned long long u64;
typedef unsigned int u32;
typedef _Float16 f16;

// ---------------------------------------------------------------------------
// R14/R15 (resubmit #2; two GPU-timeout rounds, audited twice): R12 fit the
// LDS-return-bus model: 48 ds_read_b128/wave/step x 8 waves x 12cy = 4608cy
// ~= 4650 measured (broadcast b128 pays full 1KB return for 16B unique). R13
// (readlane) regressed: VALU funnel. Arch-VGPR cap 128 is immovable (2
// rounds) -> fit it: thread (u,ch) owns ALL 4 gate rows of unit u over
// col-half ch. h-broadcast 32->16 instrs/wave; weights 256 words = 96
// arch-pinned + 128 AGPR (accvgpr_read fused into dot2 asm, VALU pipe) + 32
// LDS (8 b128/wave). Gates in-thread -> no fo exchange, ONE barrier/step.
// Cross-half reduce = 4 shfl_xor32. Model: DS ~2300cy/CU, VALU ~1700cy/SIMD
// -> ~2700cy step vs 4650. [R15 fix: weight LDS region is 64KB; hpk/ring at
// 65536 (16384 overlapped gate chunks g>=1 -> corruption). Dyn LDS 73728.]
// ---------------------------------------------------------------------------

__device__ __forceinline__ float sigmoidf_(float x) { return 1.0f / (1.0f + __expf(-x)); }
__device__ __forceinline__ float tanhf_(float x) { return 1.0f - 2.0f / (__expf(2.0f * x) + 1.0f); }

// f32 -> packed 2xf16, round-to-nearest-even (NOT cvt_pkrtz: RTZ bias would
// accumulate over 2048 steps).
__device__ __forceinline__ u32 pk2h(float a, float b) {
    unsigned short ua = __builtin_bit_cast(unsigned short, (f16)a);
    unsigned short ub = __builtin_bit_cast(unsigned short, (f16)b);
    return (u32)ua | ((u32)ub << 16);
}
__device__ __forceinline__ float lo16f(u32 v) { return (float)__builtin_bit_cast(f16, (unsigned short)(v & 0xffffu)); }
__device__ __forceinline__ float hi16f(u32 v) { return (float)__builtin_bit_cast(f16, (unsigned short)(v >> 16)); }

__device__ __forceinline__ void light_barrier() {
    __asm__ volatile("s_waitcnt lgkmcnt(0)\n\ts_barrier" ::: "memory");
}

// Tagged u64 {tag<<32 | payload}: payload inside the atomic word -> RELAXED
// agent-scope ops, no fences (proven pattern).
__device__ __forceinline__ u64 ld_rlx(const u64* p) {
    return __hip_atomic_load(p, __ATOMIC_RELAXED, __HIP_MEMORY_SCOPE_AGENT);
}
__device__ __forceinline__ void st_rlx(u64* p, u64 v) {
    __hip_atomic_store(p, v, __ATOMIC_RELAXED, __HIP_MEMORY_SCOPE_AGENT);
}
__device__ __forceinline__ void pub_u32(u64* p, u32 tag, u32 pay) { st_rlx(p, ((u64)tag << 32) | (u64)pay); }
__device__ __forceinline__ void pub_f32(u64* p, u32 tag, float x) { pub_u32(p, tag, __float_as_uint(x)); }
// spin until tag matches; v0 is a previously-issued (overlapped) load of *p.
__device__ __forceinline__ u32 spin_u32(const u64* p, u32 tag, u64 v0) {
    u64 v = v0;
    while ((u32)(v >> 32) != tag) v = ld_rlx(p);
    return (u32)v;
}

// force arch-VGPR / AGPR residency across the step loop.
__device__ __forceinline__ void pin_v(u32& v) { __asm__ volatile("" : "+v"(v)); }
__device__ __forceinline__ void pin_a(u32& v) { __asm__ volatile("" : "+a"(v)); }

// packed-f16 dot2, f32 accumulator, arch-VGPR weight
#define DOT2(ACC, W, H) __asm__("v_dot2_f32_f16 %0, %1, %2, %0" : "+v"(ACC) : "v"(W), "v"(H))
// AGPR-resident weight: fused accvgpr_read + dot2 in ONE asm (scheduler can't
// hoist the read away from its use -> no arch-pressure blowup).
#define DOT2A(ACC, W, H) do { u32 _t;                                          \
    __asm__("v_accvgpr_read_b32 %1, %2\n\tv_dot2_f32_f16 %0, %1, %3, %0"       \
            : "+v"(ACC), "=&v"(_t) : "a"(W), "v"(H)); } while (0)

// ---------------------------------------------------------------------------
// Per-thread matvec: unit u's 4 gate rows x 128 cols (half ch). h = 128
// packed words in LDS; this thread reads words [64ch, 64ch+64) as 16
// broadcast b128 (16 instrs/wave, half-wave granularity, 2-way bank alias =
// free). Weights: rel words 0..23 arch, 24..55 AGPR, 56..63 LDS chunk-major
// (addr=((g*2+i)*512+tid)*16, lanes consecutive -> conflict-free).
// ---------------------------------------------------------------------------
__device__ __forceinline__ void mv128(const u32 (&wV)[4][24], const u32 (&wG)[4][32],
                                      const u32* __restrict__ hp, const char* wl,
                                      int tid, int ch, float (&a)[4])
{
    const u32* hc = hp + (ch << 6);
    a[0] = a[1] = a[2] = a[3] = 0.f;
#pragma unroll
    for (int i = 0; i < 6; i++) {            // arch chunks: rel words 4i..4i+3
        const uint4 h4 = *(const uint4*)(hc + 4 * i);
#pragma unroll
        for (int g = 0; g < 4; g++) {
            DOT2(a[g], wV[g][4*i+0], h4.x);
            DOT2(a[g], wV[g][4*i+1], h4.y);
            DOT2(a[g], wV[g][4*i+2], h4.z);
            DOT2(a[g], wV[g][4*i+3], h4.w);
        }
    }
#pragma unroll
    for (int i = 0; i < 8; i++) {            // AGPR chunks: rel words 24..55
        const uint4 h4 = *(const uint4*)(hc + 24 + 4 * i);
#pragma unroll
        for (int g = 0; g < 4; g++) {
            DOT2A(a[g], wG[g][4*i+0], h4.x);
            DOT2A(a[g], wG[g][4*i+1], h4.y);
            DOT2A(a[g], wG[g][4*i+2], h4.z);
            DOT2A(a[g], wG[g][4*i+3], h4.w);
        }
    }
#pragma unroll
    for (int i = 0; i < 2; i++) {            // LDS chunks: rel words 56..63
        const uint4 h4 = *(const uint4*)(hc + 56 + 4 * i);
#pragma unroll
        for (int g = 0; g < 4; g++) {
            const uint4 w4 = *(const uint4*)(wl + (size_t)(((g * 2 + i) * 512 + tid) << 4));
            DOT2(a[g], w4.x, h4.x);
            DOT2(a[g], w4.y, h4.y);
            DOT2(a[g], w4.z, h4.z);
            DOT2(a[g], w4.w, h4.w);
        }
    }
}

// Load + convert: rows {u, 256+u, 512+u, 768+u}, cols [128ch, 128ch+128).
// rel cols 0..47 -> arch words 0..23; 48..111 -> AGPR 24..55; 112..127 -> LDS.
__device__ __forceinline__ void load_w(const float* __restrict__ Wm, int u, int ch, int tid,
                                       u32 (&wV)[4][24], u32 (&wG)[4][32], char* wl)
{
#pragma unroll
    for (int g = 0; g < 4; g++) {
        const float* base = Wm + (size_t)(256 * g + u) * HID + 128 * ch;
#pragma unroll
        for (int k = 0; k < 12; k++) {
            const float4 f = *(const float4*)(base + 4 * k);
            wV[g][2*k] = pk2h(f.x, f.y); wV[g][2*k+1] = pk2h(f.z, f.w);
        }
#pragma unroll
        for (int k = 0; k < 16; k++) {
            const float4 f = *(const float4*)(base + 48 + 4 * k);
            wG[g][2*k] = pk2h(f.x, f.y); wG[g][2*k+1] = pk2h(f.z, f.w);
        }
#pragma unroll
        for (int i = 0; i < 2; i++) {
            const float4 f0 = *(const float4*)(base + 112 + 8 * i);
            const float4 f1 = *(const float4*)(base + 112 + 8 * i + 4);
            *(uint4*)(wl + (size_t)(((g * 2 + i) * 512 + tid) << 4)) =
                make_uint4(pk2h(f0.x, f0.y), pk2h(f0.z, f0.w), pk2h(f1.x, f1.y), pk2h(f1.z, f1.w));
        }
    }
#pragma unroll
    for (int g = 0; g < 4; g++) {
#pragma unroll
        for (int k = 0; k < 24; k++) pin_v(wV[g][k]);
#pragma unroll
        for (int k = 0; k < 32; k++) pin_a(wG[g][k]);
    }
}

// ---------------------------------------------------------------------------
// Precompute layer-0 input projection (K=8) + both biases, packed f16 pairs:
// xp16[b][s][p] = pack(row p, row p+512): p<256 -> (i_p, g_p); p>=256 ->
// (f, o). Fused kernel thread (u, ch) loads word u + 256*ch. (unchanged)
// ---------------------------------------------------------------------------
__global__ __launch_bounds__(256) void xproj_kernel(
    const float* __restrict__ x, const float* __restrict__ w_ih0,
    const float* __restrict__ b_ih0, const float* __restrict__ b_hh0,
    u32* __restrict__ xp16)
{
    const int blk = blockIdx.x;
    const int b = blk >> 7;
    const int s0 = (blk & 127) << 4;
    const int t = threadIdx.x;
    __shared__ float xs[16][8];
    if (t < 128) xs[t >> 3][t & 7] = x[((size_t)b * SEQ + s0 + (t >> 3)) * IN + (t & 7)];
    float w0[8], w1[8], w2[8], w3[8];
#pragma unroll
    for (int k = 0; k < 8; k++) {
        w0[k] = w_ih0[(size_t)(t)       * IN + k];
        w1[k] = w_ih0[(size_t)(t + 512) * IN + k];
        w2[k] = w_ih0[(size_t)(t + 256) * IN + k];
        w3[k] = w_ih0[(size_t)(t + 768) * IN + k];
    }
    const float z0 = b_ih0[t]       + b_hh0[t];
    const float z1 = b_ih0[t + 512] + b_hh0[t + 512];
    const float z2 = b_ih0[t + 256] + b_hh0[t + 256];
    const float z3 = b_ih0[t + 768] + b_hh0[t + 768];
    __syncthreads();
#pragma unroll
    for (int si = 0; si < 16; si++) {
        float d0 = z0, d1 = z1, d2 = z2, d3 = z3;
#pragma unroll
        for (int k = 0; k < 8; k++) {
            const float xk = xs[si][k];
            d0 += w0[k] * xk; d1 += w1[k] * xk; d2 += w2[k] * xk; d3 += w3[k] * xk;
        }
        u32* o = xp16 + ((size_t)b * SEQ + s0 + si) * 512;
        o[t]       = pk2h(d0, d1);
        o[t + 256] = pk2h(d2, d3);
    }
}

// ---------------------------------------------------------------------------
// Fused 2-layer LSTM, one CU per (batch, stage). Grid = 24:
//   bid&7 = batch, bid>>3 = stage: 0=L0, 1=P (w_ih1@h0), 2=L1.
// Thread (u = wv*32+(lane&31), ch = lane>>5) owns unit u's 4 gate rows over
// col-half ch. ONE barrier/step. Streams (tagged LLC rings + progress words)
// unchanged from R12.
// LDS map: [0, 65536) weight chunks; [65536, +) hpk (L0/L1, 1KB) / ring (P, 4KB).
// ---------------------------------------------------------------------------
__global__
__attribute__((amdgpu_flat_work_group_size(512, 512)))
__attribute__((amdgpu_waves_per_eu(2, 2)))
void lstm_fused(
    const u32* __restrict__ xp16,
    const float* __restrict__ w_hh0,
    const float* __restrict__ w_ih1, const float* __restrict__ b_ih1, const float* __restrict__ b_hh1,
    const float* __restrict__ w_hh1,
    u64* __restrict__ h0r, u64* __restrict__ xpr, u64* __restrict__ progs,
    float* __restrict__ hbuf)
{
    extern __shared__ char smem[];
    char* wl = smem;                       // [0, 65536): LDS weight chunks
    const int bid = blockIdx.x;
    const int b = bid & 7, stage = bid >> 3;
    const int t = threadIdx.x;
    const int lane = t & 63;
    const int u = (t >> 6) * 32 + (lane & 31);
    const int ch = (lane >> 5) & 1;
    const u32 MHI = 0x4C50524Fu;

    u64* h0rb = h0r + (size_t)b * 32 * 128;
    u64* xpb  = xpr + (size_t)b * 32 * G4;

    // progress resets FIRST (before the slow weight load) so readers' first
    // checks (~20us in) can never see a stale value from a previous run.
    if (stage == 1 && t == 0) st_rlx(&progs[8 + b], (u64)MHI << 32);
    if (stage == 2 && t == 0) st_rlx(&progs[b],     (u64)MHI << 32);

    u32 wV[4][24], wG[4][32];
    const float* Wm = (stage == 0) ? w_hh0 : (stage == 1) ? w_ih1 : w_hh1;
    load_w(Wm, u, ch, t, wV, wG, wl);

    if (stage == 0) {
        // ================= L0: full layer-0 recurrence on one CU ===========
        u32* hpk = (u32*)(smem + 65536);              // [2][128] packed h
        if (t < 256) hpk[t] = 0u;
        const u32* xpp = xp16 + (size_t)b * SEQ * 512 + (u + 256 * ch);
        u32 xv = xpp[0];
        u32 xn = xpp[512];
        float c = 0.f;
        __syncthreads();
        for (int s = 0; s < SEQ; s++) {
            const int cur = s & 1;
            float a[4];
            mv128(wV, wG, hpk + cur * 128, wl, t, ch, a);
            // xp: ch0 word u = (i,g); ch1 word 256+u = (f,o)
            a[ch]     += lo16f(xv);
            a[2 + ch] += hi16f(xv);
            const float s0 = a[0] + __shfl_xor(a[0], 32, 64);
            const float s1 = a[1] + __shfl_xor(a[1], 32, 64);
            const float s2 = a[2] + __shfl_xor(a[2], 32, 64);
            const float s3 = a[3] + __shfl_xor(a[3], 32, 64);
            const float iv = sigmoidf_(s0);
            const float fv = sigmoidf_(s1);
            const float gv = tanhf_(s2);
            const float ov = sigmoidf_(s3);
            c = fv * c + iv * gv;
            const float hv = ov * tanhf_(c);
            const u32 tag = (u32)(s + 1);
            const int nb = __builtin_amdgcn_update_dpp(0, __float_as_int(hv), 0xB1, 0xF, 0xF, false);
            if (ch == 0 && (lane & 1) == 0) {
                const u32 pk = pk2h(hv, __int_as_float(nb));
                hpk[(cur ^ 1) * 128 + (u >> 1)] = pk;
                pub_u32(&h0rb[(size_t)(s & 31) * 128 + (u >> 1)], tag, pk);
            }
            xv = xn;
            if (s + 2 < SEQ) xn = xpp[(size_t)(s + 2) * 512];
            if (t == 0 && ((s + 1) & 7) == 0 && s >= 23) {   // gate slots vs P
                u64 v; do { v = ld_rlx(&progs[8 + b]); }
                while (!((u32)(v >> 32) == MHI && (u32)v >= (u32)(s - 23)));
            }
            light_barrier();
        }
    } else if (stage == 1) {
        // ================= P: xp[s] = w_ih1 @ h0[s] + biases ===============
        u32* ring = (u32*)(smem + 65536);             // [8][128] packed h0
        const int pr0 = u + 256 * ch;                 // gate ch row
        const int pr1 = u + 512 + 256 * ch;           // gate 2+ch row
        const float bb0 = b_ih1[pr0] + b_hh1[pr0];
        const float bb1 = b_ih1[pr1] + b_hh1[pr1];
        if (t < 128) {                                // prefill h0[0], h0[1]
            ring[t]       = spin_u32(&h0rb[t],       1u, ld_rlx(&h0rb[t]));
            ring[128 + t] = spin_u32(&h0rb[128 + t], 2u, ld_rlx(&h0rb[128 + t]));
        }
        u64 pend = 0;
        if (t < 128) pend = ld_rlx(&h0rb[(size_t)2 * 128 + t]);
        __syncthreads();
        for (int s = 0; s < SEQ; s++) {
            float a[4];
            mv128(wV, wG, ring + (s & 7) * 128, wl, t, ch, a);
            // check overlapped poll (h0[s+2]) BEFORE issuing this step's stores
            u32 hv2 = 0;
            if (t < 128 && s + 2 < SEQ)
                hv2 = spin_u32(&h0rb[(size_t)((s + 2) & 31) * 128 + t], (u32)(s + 3), pend);
            const float s0 = a[0] + __shfl_xor(a[0], 32, 64);
            const float s1 = a[1] + __shfl_xor(a[1], 32, 64);
            const float s2 = a[2] + __shfl_xor(a[2], 32, 64);
            const float s3 = a[3] + __shfl_xor(a[3], 32, 64);
            const u32 tag = (u32)(s + 1);
            u64* slot = xpb + (size_t)(s & 31) * G4;
            pub_f32(slot + pr0, tag, (ch ? s1 : s0) + bb0);
            pub_f32(slot + pr1, tag, (ch ? s3 : s2) + bb1);
            if (t < 128 && s + 2 < SEQ) {
                ring[((s + 2) & 7) * 128 + t] = hv2;
                if (s + 3 < SEQ) pend = ld_rlx(&h0rb[(size_t)((s + 3) & 31) * 128 + t]);
            }
            if (t == 0 && (s & 7) == 7)
                st_rlx(&progs[8 + b], ((u64)MHI << 32) | (u64)(u32)(s + 1));
            if (t == 0 && ((s + 1) & 7) == 0 && s >= 23) {   // gate xpr slots vs L1
                u64 v; do { v = ld_rlx(&progs[b]); }
                while (!((u32)(v >> 32) == MHI && (u32)v >= (u32)(s - 23)));
            }
            light_barrier();
        }
    } else {
        // ================= L1: full layer-1 recurrence on one CU ===========
        u32* hpk = (u32*)(smem + 65536);
        float* ho = hbuf + (size_t)b * SEQ * HID;
        const int pr0 = u + 256 * ch;
        const int pr1 = u + 512 + 256 * ch;
        if (t < 256) hpk[t] = 0u;
        float xv0 = __uint_as_float(spin_u32(&xpb[pr0], 1u, ld_rlx(&xpb[pr0])));
        float xv1 = __uint_as_float(spin_u32(&xpb[pr1], 1u, ld_rlx(&xpb[pr1])));
        u64 p0 = ld_rlx(&xpb[(size_t)1 * G4 + pr0]);
        u64 p1 = ld_rlx(&xpb[(size_t)1 * G4 + pr1]);
        float c = 0.f;
        __syncthreads();
        for (int s = 0; s < SEQ; s++) {
            const int cur = s & 1;
            float a[4];
            mv128(wV, wG, hpk + cur * 128, wl, t, ch, a);
            float xn0 = 0.f, xn1 = 0.f;
            if (s + 1 < SEQ) {   // overlapped polls (xp[s+1])
                xn0 = __uint_as_float(spin_u32(&xpb[(size_t)((s + 1) & 31) * G4 + pr0], (u32)(s + 2), p0));
                xn1 = __uint_as_float(spin_u32(&xpb[(size_t)((s + 1) & 31) * G4 + pr1], (u32)(s + 2), p1));
            }
            a[ch]     += xv0;   // ch0: i ; ch1: f
            a[2 + ch] += xv1;   // ch0: g ; ch1: o
            const float s0 = a[0] + __shfl_xor(a[0], 32, 64);
            const float s1 = a[1] + __shfl_xor(a[1], 32, 64);
            const float s2 = a[2] + __shfl_xor(a[2], 32, 64);
            const float s3 = a[3] + __shfl_xor(a[3], 32, 64);
            const float iv = sigmoidf_(s0);
            const float fv = sigmoidf_(s1);
            const float gv = tanhf_(s2);
            const float ov = sigmoidf_(s3);
            c = fv * c + iv * gv;
            const float hv = ov * tanhf_(c);
            const u32 tag = (u32)(s + 1);
            if (ch == 0) ho[(size_t)s * HID + u] = hv;
            const int nb = __builtin_amdgcn_update_dpp(0, __float_as_int(hv), 0xB1, 0xF, 0xF, false);
            if (ch == 0 && (lane & 1) == 0)
                hpk[(cur ^ 1) * 128 + (u >> 1)] = pk2h(hv, __int_as_float(nb));
            xv0 = xn0; xv1 = xn1;
            if (s + 2 < SEQ) {
                p0 = ld_rlx(&xpb[(size_t)((s + 2) & 31) * G4 + pr0]);
                p1 = ld_rlx(&xpb[(size_t)((s + 2) & 31) * G4 + pr1]);
            }
            if (t == 0 && (s & 7) == 7)
                st_rlx(&progs[b], ((u64)MHI << 32) | (u64)(u32)(s + 1));
            light_barrier();
        }
    }
}

// ---------------------------------------------------------------------------
// K and V projections in one launch (blockIdx.z selects). NT GEMM,
// 128x128x16 tiles, 256 threads, 8x8 micro-tile. (unchanged)
// ---------------------------------------------------------------------------
__global__ __launch_bounds__(256) void gemm_kv(
    const float* __restrict__ A,
    const float* __restrict__ Wk, const float* __restrict__ bk,
    const float* __restrict__ Wv, const float* __restrict__ bv,
    float* __restrict__ Ck, float* __restrict__ Cv, int M, int N, int K)
{
    const float* W    = blockIdx.z ? Wv : Wk;
    const float* bias = blockIdx.z ? bv : bk;
    float*       C    = blockIdx.z ? Cv : Ck;

    __shared__ float As[16][132];
    __shared__ float Bs[16][132];
    const int tid = threadIdx.x;
    const int tx = tid & 15;
    const int ty = tid >> 4;
    const int bm = blockIdx.x * 128;
    const int bn = blockIdx.y * 128;
    const int lrow = tid >> 1;
    const int lk = (tid & 1) * 8;

    float acc[8][8] = {};

    for (int k0 = 0; k0 < K; k0 += 16) {
        const float* ap = A + (size_t)(bm + lrow) * K + k0 + lk;
        const float* wp = W + (size_t)(bn + lrow) * K + k0 + lk;
        const float4 a0 = *(const float4*)ap;
        const float4 a1 = *(const float4*)(ap + 4);
        const float4 w0 = *(const float4*)wp;
        const float4 w1 = *(const float4*)(wp + 4);
        __syncthreads();
        As[lk+0][lrow] = a0.x; As[lk+1][lrow] = a0.y; As[lk+2][lrow] = a0.z; As[lk+3][lrow] = a0.w;
        As[lk+4][lrow] = a1.x; As[lk+5][lrow] = a1.y; As[lk+6][lrow] = a1.z; As[lk+7][lrow] = a1.w;
        Bs[lk+0][lrow] = w0.x; Bs[lk+1][lrow] = w0.y; Bs[lk+2][lrow] = w0.z; Bs[lk+3][lrow] = w0.w;
        Bs[lk+4][lrow] = w1.x; Bs[lk+5][lrow] = w1.y; Bs[lk+6][lrow] = w1.z; Bs[lk+7][lrow] = w1.w;
        __syncthreads();
#pragma unroll
        for (int k = 0; k < 16; k++) {
            const float4 av0 = *(const float4*)(&As[k][ty * 4]);
            const float4 av1 = *(const float4*)(&As[k][64 + ty * 4]);
            const float4 bv0 = *(const float4*)(&Bs[k][tx * 4]);
            const float4 bv1 = *(const float4*)(&Bs[k][64 + tx * 4]);
            const float ar[8] = {av0.x, av0.y, av0.z, av0.w, av1.x, av1.y, av1.z, av1.w};
            const float br[8] = {bv0.x, bv0.y, bv0.z, bv0.w, bv1.x, bv1.y, bv1.z, bv1.w};
#pragma unroll
            for (int i = 0; i < 8; i++)
#pragma unroll
                for (int j = 0; j < 8; j++) acc[i][j] += ar[i] * br[j];
        }
    }

    const int c0 = bn + tx * 4, c1 = bn + 64 + tx * 4;
    const float4 bb0 = *(const float4*)(bias + c0);
    const float4 bb1 = *(const float4*)(bias + c1);
#pragma unroll
    for (int ih = 0; ih < 2; ih++)
#pragma unroll
        for (int i = 0; i < 4; i++) {
            const int row = bm + ih * 64 + ty * 4 + i;
            const int ai = ih * 4 + i;
            float4 o0, o1;
            o0.x = acc[ai][0] + bb0.x; o0.y = acc[ai][1] + bb0.y;
            o0.z = acc[ai][2] + bb0.z; o0.w = acc[ai][3] + bb0.w;
            o1.x = acc[ai][4] + bb1.x; o1.y = acc[ai][5] + bb1.y;
            o1.z = acc[ai][6] + bb1.z; o1.w = acc[ai][7] + bb1.w;
            *(float4*)(C + (size_t)row * N + c0) = o0;
            *(float4*)(C + (size_t)row * N + c1) = o1;
        }
}

// ---------------------------------------------------------------------------
// Q projection at the last position only. (unchanged)
// ---------------------------------------------------------------------------
__global__ __launch_bounds__(256) void qlast_kernel(
    const float* __restrict__ h1, const float* __restrict__ wq,
    const float* __restrict__ bq, float* __restrict__ qout)
{
    const int b = blockIdx.x;
    const int t = threadIdx.x;
    __shared__ __align__(16) float hs[HID];
    hs[t] = h1[((size_t)b * SEQ + (SEQ - 1)) * HID + t];
    __syncthreads();
    const float4* wr = (const float4*)(wq + (size_t)t * HID);
    float acc = 0.0f;
#pragma unroll
    for (int k = 0; k < 64; k++) {
        const float4 wv = wr[k];
        const float4 hv = ((const float4*)hs)[k];
        acc += wv.x*hv.x + wv.y*hv.y + wv.z*hv.z + wv.w*hv.w;
    }
    qout[b * HID + t] = acc + bq[t];
}

// ---------------------------------------------------------------------------
// Decode attention at query S-1 with multiplicative decay on scores. (unchanged)
// ---------------------------------------------------------------------------
__global__ __launch_bounds__(256) void attn_kernel(
    const float* __restrict__ Kb, const float* __restrict__ Vb,
    const float* __restrict__ q, float* __restrict__ attn)
{
    const int b = blockIdx.x >> 2;
    const int h = blockIdx.x & 3;
    const int tid = threadIdx.x;

    __shared__ __align__(16) float qs[64];
    __shared__ float sc[SEQ];
    __shared__ float red[256];
    __shared__ float part[4][64];

    if (tid < 64) qs[tid] = q[b * HID + h * 64 + tid];
    __syncthreads();

    const float LN095 = -0.051293294387550533f;  // ln(0.95)
    for (int k = tid; k < SEQ; k += 256) {
        const float4* kr = (const float4*)(Kb + ((size_t)b * SEQ + k) * HID + h * 64);
        float acc = 0.0f;
#pragma unroll
        for (int d = 0; d < 16; d++) {
            const float4 kv = kr[d];
            const float4 qv = ((const float4*)qs)[d];
            acc += kv.x*qv.x + kv.y*qv.y + kv.z*qv.z + kv.w*qv.w;
        }
        const float dec = __expf(LN095 * (float)(SEQ - 1 - k));
        sc[k] = acc * 0.125f * dec;
    }
    __syncthreads();

    float m = -INFINITY;
    for (int k = tid; k < SEQ; k += 256) m = fmaxf(m, sc[k]);
    red[tid] = m;
    for (int off = 128; off > 0; off >>= 1) {
        __syncthreads();
        if (tid < off) red[tid] = fmaxf(red[tid], red[tid + off]);
    }
    __syncthreads();
    const float mx = red[0];

    float local = 0.0f;
    for (int k = tid; k < SEQ; k += 256) {
        const float p = expf(sc[k] - mx);
        sc[k] = p;
        local += p;
    }
    __syncthreads();
    red[tid] = local;
    for (int off = 128; off > 0; off >>= 1) {
        __syncthreads();
        if (tid < off) red[tid] += red[tid + off];
    }
    __syncthreads();
    const float total = red[0];

    const int chunk = tid >> 6;
    const int d = tid & 63;
    float acc = 0.0f;
    const int k0 = chunk * (SEQ / 4), k1 = (chunk + 1) * (SEQ / 4);
    for (int k = k0; k < k1; k++)
        acc += sc[k] * Vb[((size_t)b * SEQ + k) * HID + h * 64 + d];
    part[chunk][d] = acc;
    __syncthreads();
    if (tid < 64) {
        const float r = (part[0][tid] + part[1][tid]) + (part[2][tid] + part[3][tid]);
        attn[b * HID + h * 64 + tid] = r / total;
    }
}

// ---------------------------------------------------------------------------
// Head: context = attn @ wo^T + bo ; mean/log_var heads (5 each). (unchanged)
// ---------------------------------------------------------------------------
__global__ __launch_bounds__(256) void head_kernel(
    const float* __restrict__ attn, const float* __restrict__ wo,
    const float* __restrict__ bo, const float* __restrict__ w_mean,
    const float* __restrict__ b_mean, const float* __restrict__ w_var,
    const float* __restrict__ b_var, float* __restrict__ out)
{
    const int b = blockIdx.x;
    const int t = threadIdx.x;
    __shared__ __align__(16) float av[HID];
    __shared__ __align__(16) float ctx[HID];
    av[t] = attn[b * HID + t];
    __syncthreads();
    {
        const float4* wr = (const float4*)(wo + (size_t)t * HID);
        float acc = 0.0f;
#pragma unroll
        for (int k = 0; k < 64; k++) {
            const float4 wv = wr[k];
            const float4 hv = ((const float4*)av)[k];
            acc += wv.x*hv.x + wv.y*hv.y + wv.z*hv.z + wv.w*hv.w;
        }
        ctx[t] = acc + bo[t];
    }
    __syncthreads();
    if (t < 5) {
        const float4* wr = (const float4*)(w_mean + (size_t)t * HID);
        float acc = 0.0f;
#pragma unroll
        for (int k = 0; k < 64; k++) {
            const float4 wv = wr[k];
            const float4 hv = ((const float4*)ctx)[k];
            acc += wv.x*hv.x + wv.y*hv.y + wv.z*hv.z + wv.w*hv.w;
        }
        out[b * 5 + t] = acc + b_mean[t];
    } else if (t >= 8 && t < 13) {
        const int m = t - 8;
        const float4* wr = (const float4*)(w_var + (size_t)m * HID);
        float acc = 0.0f;
#pragma unroll
        for (int k = 0; k < 64; k++) {
            const float4 wv = wr[k];
            const float4 hv = ((const float4*)ctx)[k];
            acc += wv.x*hv.x + wv.y*hv.y + wv.z*hv.z + wv.w*hv.w;
        }
        out[BATCH * 5 + b * 5 + m] = acc + b_var[m];
    }
}

// ---------------------------------------------------------------------------
extern "C" void kernel_launch(void* const* d_in, const int* in_sizes, int n_in,
                              void* d_out, int out_size, void* d_ws, size_t ws_size,
                              hipStream_t stream) {
    const float* x      = (const float*)d_in[0];
    const float* w_ih0  = (const float*)d_in[1];
    const float* w_hh0  = (const float*)d_in[2];
    const float* b_ih0  = (const float*)d_in[3];
    const float* b_hh0  = (const float*)d_in[4];
    const float* w_ih1  = (const float*)d_in[5];
    const float* w_hh1  = (const float*)d_in[6];
    const float* b_ih1  = (const float*)d_in[7];
    const float* b_hh1  = (const float*)d_in[8];
    const float* wq     = (const float*)d_in[9];
    const float* bq     = (const float*)d_in[10];
    const float* wk     = (const float*)d_in[11];
    const float* bk     = (const float*)d_in[12];
    const float* wvv    = (const float*)d_in[13];
    const float* bv     = (const float*)d_in[14];
    const float* wo     = (const float*)d_in[15];
    const float* bo     = (const float*)d_in[16];
    const float* w_mean = (const float*)d_in[17];
    const float* b_mean = (const float*)d_in[18];
    const float* w_var  = (const float*)d_in[19];
    const float* b_var  = (const float*)d_in[20];
    float* out = (float*)d_out;

    // ws layout (bytes), ~50.3 MB peak:
    //  [0, 16M)            hbuf  (plain h1; LSTM writes, KV/qlast read)
    //  [16M, 48M)          xp16  (f16-pair layer-0 input proj)  -> Kbuf|Vbuf after
    //  [48M, 48M+256K)     h0r   (32-deep tagged packed-h0 ring) -> qbuf|abuf after
    //  [48M+256K, +2M)     xpr   (32-deep tagged f32 xp ring)
    //  [52690944, +128B)   progs (L1prog[8], Pprog[8])
    char* wsb = (char*)d_ws;
    float* hbuf = (float*)wsb;
    u32*  xp16  = (u32*)(wsb + 16777216);
    u64*  h0r   = (u64*)(wsb + 50331648);
    u64*  xpr   = (u64*)(wsb + 50593792);
    u64*  progs = (u64*)(wsb + 52690944);
    float* Kbuf = (float*)(wsb + 16777216);
    float* Vbuf = (float*)(wsb + 33554432);
    float* qbuf = (float*)(wsb + 50331648);
    float* abuf = (float*)(wsb + 50331648 + 8192);

    static bool attr_done = false;
    if (!attr_done) {
        hipFuncSetAttribute(reinterpret_cast<const void*>(lstm_fused),
                            hipFuncAttributeMaxDynamicSharedMemorySize, 73728);
        attr_done = true;
    }

    // 1. layer-0 input projection (f16 pairs, biases folded)
    xproj_kernel<<<1024, 256, 0, stream>>>(x, w_ih0, b_ih0, b_hh0, xp16);
    // 2. fused single-CU-per-stage pipelined 2-layer LSTM
    //    (dyn smem 72KB: 64KB weight chunks + 4KB ring + slack)
    lstm_fused<<<24, 512, 73728, stream>>>(xp16, w_hh0, w_ih1, b_ih1, b_hh1, w_hh1,
                                           h0r, xpr, progs, hbuf);
    // 3. K and V projections (one launch)
    gemm_kv<<<dim3(128, 2, 2), 256, 0, stream>>>(hbuf, wk, bk, wvv, bv, Kbuf, Vbuf, 16384, 256, 256);
    // 4. Q at last position
    qlast_kernel<<<BATCH, 256, 0, stream>>>(hbuf, wq, bq, qbuf);
    // 5. decode attention with decay
    attn_kernel<<<BATCH * 4, 256, 0, stream>>>(Kbuf, Vbuf, qbuf, abuf);
    // 6. output proj + gaussian head
    head_kernel<<<BATCH, 256, 0, stream>>>(abuf, wo, bo, w_mean, b_mean, w_var, b_var, out);
}

// Round 8
// 4720.305 us; speedup vs baseline: 1.2691x; 1.2691x over previous
//
#include <hip/hip_runtime.h>
#include <math.h>

#define BATCH 8
#define SEQ   2048
#define IN    8
#define HID   256
#define G4    1024   // 4*HID

typedef unsigned long long u64;
typedef unsigned int u32;
typedef _Float16 f16;

// ---------------------------------------------------------------------------
// R16: R15 (explicit 96-arch + 128-AGPR DOT2A split) regressed to 5797us:
// VALUBusy 58%/active = ~3900cy VALU/step vs ~1700 modeled. Cause: DOT2A's
// per-site "=&v" temp with ZERO arch headroom (96 pinned + 35 working = 131 >
// 128 cap) -> allocator shuffled live values around every one of the 128
// DOT2A sites (~+512 instrs). R12's compiler-managed AGPR residency (pin
// "+v", allocator overflows to AGPR with its own well-scheduled reads) ran
// the same volume at 2400cy. R16 keeps R15's structural wins (17 h-broadcast
// vs 32, ONE barrier/step, 4 gates in-thread, cross-half shfl reduce) and
// reverts to the R12 register strategy with headroom: 208 words pinned "+v"
// (~93 arch + ~115 AGPR), 48 words LDS (12 b128/wave). Model: DS ~2900cy/CU,
// VALU ~1700cy/SIMD -> step ~3000-3300cy vs R12's 4650.
// ---------------------------------------------------------------------------

__device__ __forceinline__ float sigmoidf_(float x) { return 1.0f / (1.0f + __expf(-x)); }
__device__ __forceinline__ float tanhf_(float x) { return 1.0f - 2.0f / (__expf(2.0f * x) + 1.0f); }

// f32 -> packed 2xf16, round-to-nearest-even (NOT cvt_pkrtz: RTZ bias would
// accumulate over 2048 steps).
__device__ __forceinline__ u32 pk2h(float a, float b) {
    unsigned short ua = __builtin_bit_cast(unsigned short, (f16)a);
    unsigned short ub = __builtin_bit_cast(unsigned short, (f16)b);
    return (u32)ua | ((u32)ub << 16);
}
__device__ __forceinline__ float lo16f(u32 v) { return (float)__builtin_bit_cast(f16, (unsigned short)(v & 0xffffu)); }
__device__ __forceinline__ float hi16f(u32 v) { return (float)__builtin_bit_cast(f16, (unsigned short)(v >> 16)); }

__device__ __forceinline__ void light_barrier() {
    __asm__ volatile("s_waitcnt lgkmcnt(0)\n\ts_barrier" ::: "memory");
}

// Tagged u64 {tag<<32 | payload}: payload inside the atomic word -> RELAXED
// agent-scope ops, no fences (proven pattern).
__device__ __forceinline__ u64 ld_rlx(const u64* p) {
    return __hip_atomic_load(p, __ATOMIC_RELAXED, __HIP_MEMORY_SCOPE_AGENT);
}
__device__ __forceinline__ void st_rlx(u64* p, u64 v) {
    __hip_atomic_store(p, v, __ATOMIC_RELAXED, __HIP_MEMORY_SCOPE_AGENT);
}
__device__ __forceinline__ void pub_u32(u64* p, u32 tag, u32 pay) { st_rlx(p, ((u64)tag << 32) | (u64)pay); }
__device__ __forceinline__ void pub_f32(u64* p, u32 tag, float x) { pub_u32(p, tag, __float_as_uint(x)); }
// spin until tag matches; v0 is a previously-issued (overlapped) load of *p.
__device__ __forceinline__ u32 spin_u32(const u64* p, u32 tag, u64 v0) {
    u64 v = v0;
    while ((u32)(v >> 32) != tag) v = ld_rlx(p);
    return (u32)v;
}

// keep converted weight words live in registers across the step loop (the
// allocator places them arch-or-AGPR and schedules its own accvgpr reads —
// R12 proved this path is clean; R15's explicit split thrashed).
__device__ __forceinline__ void pin_v(u32& v) { __asm__ volatile("" : "+v"(v)); }

// packed-f16 dot2, f32 accumulator (full-rate VALU, 2 FMA/instr)
#define DOT2(ACC, W, H) __asm__("v_dot2_f32_f16 %0, %1, %2, %0" : "+v"(ACC) : "v"(W), "v"(H))

// ---------------------------------------------------------------------------
// Per-thread matvec: unit u's 4 gate rows x 128 cols (half ch). h = 128
// packed words in LDS; this thread reads words [64ch, 64ch+64) as 17
// broadcast b128 (half-wave granularity, 2-addr alias = free). Weights: rel
// words 0..51 pinned registers, 52..63 LDS chunk-major
// (addr=((g*3+i)*512+tid)*16, lanes consecutive -> conflict-free).
// ---------------------------------------------------------------------------
__device__ __forceinline__ void mv128(const u32 (&wW)[4][52],
                                      const u32* __restrict__ hp, const char* wl,
                                      int tid, int ch, float (&a)[4])
{
    const u32* hc = hp + (ch << 6);
    a[0] = a[1] = a[2] = a[3] = 0.f;
#pragma unroll
    for (int i = 0; i < 13; i++) {           // reg chunks: rel words 4i..4i+3
        const uint4 h4 = *(const uint4*)(hc + 4 * i);
#pragma unroll
        for (int g = 0; g < 4; g++) {
            DOT2(a[g], wW[g][4*i+0], h4.x);
            DOT2(a[g], wW[g][4*i+1], h4.y);
            DOT2(a[g], wW[g][4*i+2], h4.z);
            DOT2(a[g], wW[g][4*i+3], h4.w);
        }
    }
#pragma unroll
    for (int i = 0; i < 3; i++) {            // LDS chunks: rel words 52..63
        const uint4 h4 = *(const uint4*)(hc + 52 + 4 * i);
#pragma unroll
        for (int g = 0; g < 4; g++) {
            const uint4 w4 = *(const uint4*)(wl + (size_t)(((g * 3 + i) * 512 + tid) << 4));
            DOT2(a[g], w4.x, h4.x);
            DOT2(a[g], w4.y, h4.y);
            DOT2(a[g], w4.z, h4.z);
            DOT2(a[g], w4.w, h4.w);
        }
    }
}

// Load + convert: rows {u, 256+u, 512+u, 768+u}, cols [128ch, 128ch+128).
// rel cols 0..103 -> pinned words 0..51; 104..127 -> LDS (3 b128/gate).
__device__ __forceinline__ void load_w(const float* __restrict__ Wm, int u, int ch, int tid,
                                       u32 (&wW)[4][52], char* wl)
{
#pragma unroll
    for (int g = 0; g < 4; g++) {
        const float* base = Wm + (size_t)(256 * g + u) * HID + 128 * ch;
#pragma unroll
        for (int k = 0; k < 26; k++) {
            const float4 f = *(const float4*)(base + 4 * k);
            wW[g][2*k] = pk2h(f.x, f.y); wW[g][2*k+1] = pk2h(f.z, f.w);
        }
#pragma unroll
        for (int i = 0; i < 3; i++) {
            const float4 f0 = *(const float4*)(base + 104 + 8 * i);
            const float4 f1 = *(const float4*)(base + 104 + 8 * i + 4);
            *(uint4*)(wl + (size_t)(((g * 3 + i) * 512 + tid) << 4)) =
                make_uint4(pk2h(f0.x, f0.y), pk2h(f0.z, f0.w), pk2h(f1.x, f1.y), pk2h(f1.z, f1.w));
        }
    }
#pragma unroll
    for (int g = 0; g < 4; g++)
#pragma unroll
        for (int k = 0; k < 52; k++) pin_v(wW[g][k]);
}

// ---------------------------------------------------------------------------
// Precompute layer-0 input projection (K=8) + both biases, packed f16 pairs:
// xp16[b][s][p] = pack(row p, row p+512): p<256 -> (i_p, g_p); p>=256 ->
// (f, o). Fused kernel thread (u, ch) loads word u + 256*ch. (unchanged)
// ---------------------------------------------------------------------------
__global__ __launch_bounds__(256) void xproj_kernel(
    const float* __restrict__ x, const float* __restrict__ w_ih0,
    const float* __restrict__ b_ih0, const float* __restrict__ b_hh0,
    u32* __restrict__ xp16)
{
    const int blk = blockIdx.x;
    const int b = blk >> 7;
    const int s0 = (blk & 127) << 4;
    const int t = threadIdx.x;
    __shared__ float xs[16][8];
    if (t < 128) xs[t >> 3][t & 7] = x[((size_t)b * SEQ + s0 + (t >> 3)) * IN + (t & 7)];
    float w0[8], w1[8], w2[8], w3[8];
#pragma unroll
    for (int k = 0; k < 8; k++) {
        w0[k] = w_ih0[(size_t)(t)       * IN + k];
        w1[k] = w_ih0[(size_t)(t + 512) * IN + k];
        w2[k] = w_ih0[(size_t)(t + 256) * IN + k];
        w3[k] = w_ih0[(size_t)(t + 768) * IN + k];
    }
    const float z0 = b_ih0[t]       + b_hh0[t];
    const float z1 = b_ih0[t + 512] + b_hh0[t + 512];
    const float z2 = b_ih0[t + 256] + b_hh0[t + 256];
    const float z3 = b_ih0[t + 768] + b_hh0[t + 768];
    __syncthreads();
#pragma unroll
    for (int si = 0; si < 16; si++) {
        float d0 = z0, d1 = z1, d2 = z2, d3 = z3;
#pragma unroll
        for (int k = 0; k < 8; k++) {
            const float xk = xs[si][k];
            d0 += w0[k] * xk; d1 += w1[k] * xk; d2 += w2[k] * xk; d3 += w3[k] * xk;
        }
        u32* o = xp16 + ((size_t)b * SEQ + s0 + si) * 512;
        o[t]       = pk2h(d0, d1);
        o[t + 256] = pk2h(d2, d3);
    }
}

// ---------------------------------------------------------------------------
// Fused 2-layer LSTM, one CU per (batch, stage). Grid = 24:
//   bid&7 = batch, bid>>3 = stage: 0=L0, 1=P (w_ih1@h0), 2=L1.
// Thread (u = wv*32+(lane&31), ch = lane>>5) owns unit u's 4 gate rows over
// col-half ch. ONE barrier/step. Streams (tagged LLC rings + progress words)
// unchanged from R12.
// LDS map: [0, 98304) weight chunks; [98304, +) hpk (L0/L1, 1KB) / ring (P, 4KB).
// ---------------------------------------------------------------------------
__global__
__attribute__((amdgpu_flat_work_group_size(512, 512)))
__attribute__((amdgpu_waves_per_eu(2, 2)))
void lstm_fused(
    const u32* __restrict__ xp16,
    const float* __restrict__ w_hh0,
    const float* __restrict__ w_ih1, const float* __restrict__ b_ih1, const float* __restrict__ b_hh1,
    const float* __restrict__ w_hh1,
    u64* __restrict__ h0r, u64* __restrict__ xpr, u64* __restrict__ progs,
    float* __restrict__ hbuf)
{
    extern __shared__ char smem[];
    char* wl = smem;                       // [0, 98304): LDS weight chunks
    const int bid = blockIdx.x;
    const int b = bid & 7, stage = bid >> 3;
    const int t = threadIdx.x;
    const int lane = t & 63;
    const int u = (t >> 6) * 32 + (lane & 31);
    const int ch = (lane >> 5) & 1;
    const u32 MHI = 0x4C50524Fu;

    u64* h0rb = h0r + (size_t)b * 32 * 128;
    u64* xpb  = xpr + (size_t)b * 32 * G4;

    // progress resets FIRST (before the slow weight load) so readers' first
    // checks (~20us in) can never see a stale value from a previous run.
    if (stage == 1 && t == 0) st_rlx(&progs[8 + b], (u64)MHI << 32);
    if (stage == 2 && t == 0) st_rlx(&progs[b],     (u64)MHI << 32);

    u32 wW[4][52];
    const float* Wm = (stage == 0) ? w_hh0 : (stage == 1) ? w_ih1 : w_hh1;
    load_w(Wm, u, ch, t, wW, wl);

    if (stage == 0) {
        // ================= L0: full layer-0 recurrence on one CU ===========
        u32* hpk = (u32*)(smem + 98304);              // [2][128] packed h
        if (t < 256) hpk[t] = 0u;
        const u32* xpp = xp16 + (size_t)b * SEQ * 512 + (u + 256 * ch);
        u32 xv = xpp[0];
        u32 xn = xpp[512];
        float c = 0.f;
        __syncthreads();
        for (int s = 0; s < SEQ; s++) {
            const int cur = s & 1;
            float a[4];
            mv128(wW, hpk + cur * 128, wl, t, ch, a);
            // xp: ch0 word u = (i,g); ch1 word 256+u = (f,o)
            a[ch]     += lo16f(xv);
            a[2 + ch] += hi16f(xv);
            const float s0 = a[0] + __shfl_xor(a[0], 32, 64);
            const float s1 = a[1] + __shfl_xor(a[1], 32, 64);
            const float s2 = a[2] + __shfl_xor(a[2], 32, 64);
            const float s3 = a[3] + __shfl_xor(a[3], 32, 64);
            const float iv = sigmoidf_(s0);
            const float fv = sigmoidf_(s1);
            const float gv = tanhf_(s2);
            const float ov = sigmoidf_(s3);
            c = fv * c + iv * gv;
            const float hv = ov * tanhf_(c);
            const u32 tag = (u32)(s + 1);
            const int nb = __builtin_amdgcn_update_dpp(0, __float_as_int(hv), 0xB1, 0xF, 0xF, false);
            if (ch == 0 && (lane & 1) == 0) {
                const u32 pk = pk2h(hv, __int_as_float(nb));
                hpk[(cur ^ 1) * 128 + (u >> 1)] = pk;
                pub_u32(&h0rb[(size_t)(s & 31) * 128 + (u >> 1)], tag, pk);
            }
            xv = xn;
            if (s + 2 < SEQ) xn = xpp[(size_t)(s + 2) * 512];
            if (t == 0 && ((s + 1) & 7) == 0 && s >= 23) {   // gate slots vs P
                u64 v; do { v = ld_rlx(&progs[8 + b]); }
                while (!((u32)(v >> 32) == MHI && (u32)v >= (u32)(s - 23)));
            }
            light_barrier();
        }
    } else if (stage == 1) {
        // ================= P: xp[s] = w_ih1 @ h0[s] + biases ===============
        u32* ring = (u32*)(smem + 98304);             // [8][128] packed h0
        const int pr0 = u + 256 * ch;                 // gate ch row
        const int pr1 = u + 512 + 256 * ch;           // gate 2+ch row
        const float bb0 = b_ih1[pr0] + b_hh1[pr0];
        const float bb1 = b_ih1[pr1] + b_hh1[pr1];
        if (t < 128) {                                // prefill h0[0], h0[1]
            ring[t]       = spin_u32(&h0rb[t],       1u, ld_rlx(&h0rb[t]));
            ring[128 + t] = spin_u32(&h0rb[128 + t], 2u, ld_rlx(&h0rb[128 + t]));
        }
        u64 pend = 0;
        if (t < 128) pend = ld_rlx(&h0rb[(size_t)2 * 128 + t]);
        __syncthreads();
        for (int s = 0; s < SEQ; s++) {
            float a[4];
            mv128(wW, ring + (s & 7) * 128, wl, t, ch, a);
            // check overlapped poll (h0[s+2]) BEFORE issuing this step's stores
            u32 hv2 = 0;
            if (t < 128 && s + 2 < SEQ)
                hv2 = spin_u32(&h0rb[(size_t)((s + 2) & 31) * 128 + t], (u32)(s + 3), pend);
            const float s0 = a[0] + __shfl_xor(a[0], 32, 64);
            const float s1 = a[1] + __shfl_xor(a[1], 32, 64);
            const float s2 = a[2] + __shfl_xor(a[2], 32, 64);
            const float s3 = a[3] + __shfl_xor(a[3], 32, 64);
            const u32 tag = (u32)(s + 1);
            u64* slot = xpb + (size_t)(s & 31) * G4;
            pub_f32(slot + pr0, tag, (ch ? s1 : s0) + bb0);
            pub_f32(slot + pr1, tag, (ch ? s3 : s2) + bb1);
            if (t < 128 && s + 2 < SEQ) {
                ring[((s + 2) & 7) * 128 + t] = hv2;
                if (s + 3 < SEQ) pend = ld_rlx(&h0rb[(size_t)((s + 3) & 31) * 128 + t]);
            }
            if (t == 0 && (s & 7) == 7)
                st_rlx(&progs[8 + b], ((u64)MHI << 32) | (u64)(u32)(s + 1));
            if (t == 0 && ((s + 1) & 7) == 0 && s >= 23) {   // gate xpr slots vs L1
                u64 v; do { v = ld_rlx(&progs[b]); }
                while (!((u32)(v >> 32) == MHI && (u32)v >= (u32)(s - 23)));
            }
            light_barrier();
        }
    } else {
        // ================= L1: full layer-1 recurrence on one CU ===========
        u32* hpk = (u32*)(smem + 98304);
        float* ho = hbuf + (size_t)b * SEQ * HID;
        const int pr0 = u + 256 * ch;
        const int pr1 = u + 512 + 256 * ch;
        if (t < 256) hpk[t] = 0u;
        float xv0 = __uint_as_float(spin_u32(&xpb[pr0], 1u, ld_rlx(&xpb[pr0])));
        float xv1 = __uint_as_float(spin_u32(&xpb[pr1], 1u, ld_rlx(&xpb[pr1])));
        u64 p0 = ld_rlx(&xpb[(size_t)1 * G4 + pr0]);
        u64 p1 = ld_rlx(&xpb[(size_t)1 * G4 + pr1]);
        float c = 0.f;
        __syncthreads();
        for (int s = 0; s < SEQ; s++) {
            const int cur = s & 1;
            float a[4];
            mv128(wW, hpk + cur * 128, wl, t, ch, a);
            float xn0 = 0.f, xn1 = 0.f;
            if (s + 1 < SEQ) {   // overlapped polls (xp[s+1])
                xn0 = __uint_as_float(spin_u32(&xpb[(size_t)((s + 1) & 31) * G4 + pr0], (u32)(s + 2), p0));
                xn1 = __uint_as_float(spin_u32(&xpb[(size_t)((s + 1) & 31) * G4 + pr1], (u32)(s + 2), p1));
            }
            a[ch]     += xv0;   // ch0: i ; ch1: f
            a[2 + ch] += xv1;   // ch0: g ; ch1: o
            const float s0 = a[0] + __shfl_xor(a[0], 32, 64);
            const float s1 = a[1] + __shfl_xor(a[1], 32, 64);
            const float s2 = a[2] + __shfl_xor(a[2], 32, 64);
            const float s3 = a[3] + __shfl_xor(a[3], 32, 64);
            const float iv = sigmoidf_(s0);
            const float fv = sigmoidf_(s1);
            const float gv = tanhf_(s2);
            const float ov = sigmoidf_(s3);
            c = fv * c + iv * gv;
            const float hv = ov * tanhf_(c);
            const u32 tag = (u32)(s + 1);
            if (ch == 0) ho[(size_t)s * HID + u] = hv;
            const int nb = __builtin_amdgcn_update_dpp(0, __float_as_int(hv), 0xB1, 0xF, 0xF, false);
            if (ch == 0 && (lane & 1) == 0)
                hpk[(cur ^ 1) * 128 + (u >> 1)] = pk2h(hv, __int_as_float(nb));
            xv0 = xn0; xv1 = xn1;
            if (s + 2 < SEQ) {
                p0 = ld_rlx(&xpb[(size_t)((s + 2) & 31) * G4 + pr0]);
                p1 = ld_rlx(&xpb[(size_t)((s + 2) & 31) * G4 + pr1]);
            }
            if (t == 0 && (s & 7) == 7)
                st_rlx(&progs[b], ((u64)MHI << 32) | (u64)(u32)(s + 1));
            light_barrier();
        }
    }
}

// ---------------------------------------------------------------------------
// K and V projections in one launch (blockIdx.z selects). NT GEMM,
// 128x128x16 tiles, 256 threads, 8x8 micro-tile. (unchanged)
// ---------------------------------------------------------------------------
__global__ __launch_bounds__(256) void gemm_kv(
    const float* __restrict__ A,
    const float* __restrict__ Wk, const float* __restrict__ bk,
    const float* __restrict__ Wv, const float* __restrict__ bv,
    float* __restrict__ Ck, float* __restrict__ Cv, int M, int N, int K)
{
    const float* W    = blockIdx.z ? Wv : Wk;
    const float* bias = blockIdx.z ? bv : bk;
    float*       C    = blockIdx.z ? Cv : Ck;

    __shared__ float As[16][132];
    __shared__ float Bs[16][132];
    const int tid = threadIdx.x;
    const int tx = tid & 15;
    const int ty = tid >> 4;
    const int bm = blockIdx.x * 128;
    const int bn = blockIdx.y * 128;
    const int lrow = tid >> 1;
    const int lk = (tid & 1) * 8;

    float acc[8][8] = {};

    for (int k0 = 0; k0 < K; k0 += 16) {
        const float* ap = A + (size_t)(bm + lrow) * K + k0 + lk;
        const float* wp = W + (size_t)(bn + lrow) * K + k0 + lk;
        const float4 a0 = *(const float4*)ap;
        const float4 a1 = *(const float4*)(ap + 4);
        const float4 w0 = *(const float4*)wp;
        const float4 w1 = *(const float4*)(wp + 4);
        __syncthreads();
        As[lk+0][lrow] = a0.x; As[lk+1][lrow] = a0.y; As[lk+2][lrow] = a0.z; As[lk+3][lrow] = a0.w;
        As[lk+4][lrow] = a1.x; As[lk+5][lrow] = a1.y; As[lk+6][lrow] = a1.z; As[lk+7][lrow] = a1.w;
        Bs[lk+0][lrow] = w0.x; Bs[lk+1][lrow] = w0.y; Bs[lk+2][lrow] = w0.z; Bs[lk+3][lrow] = w0.w;
        Bs[lk+4][lrow] = w1.x; Bs[lk+5][lrow] = w1.y; Bs[lk+6][lrow] = w1.z; Bs[lk+7][lrow] = w1.w;
        __syncthreads();
#pragma unroll
        for (int k = 0; k < 16; k++) {
            const float4 av0 = *(const float4*)(&As[k][ty * 4]);
            const float4 av1 = *(const float4*)(&As[k][64 + ty * 4]);
            const float4 bv0 = *(const float4*)(&Bs[k][tx * 4]);
            const float4 bv1 = *(const float4*)(&Bs[k][64 + tx * 4]);
            const float ar[8] = {av0.x, av0.y, av0.z, av0.w, av1.x, av1.y, av1.z, av1.w};
            const float br[8] = {bv0.x, bv0.y, bv0.z, bv0.w, bv1.x, bv1.y, bv1.z, bv1.w};
#pragma unroll
            for (int i = 0; i < 8; i++)
#pragma unroll
                for (int j = 0; j < 8; j++) acc[i][j] += ar[i] * br[j];
        }
    }

    const int c0 = bn + tx * 4, c1 = bn + 64 + tx * 4;
    const float4 bb0 = *(const float4*)(bias + c0);
    const float4 bb1 = *(const float4*)(bias + c1);
#pragma unroll
    for (int ih = 0; ih < 2; ih++)
#pragma unroll
        for (int i = 0; i < 4; i++) {
            const int row = bm + ih * 64 + ty * 4 + i;
            const int ai = ih * 4 + i;
            float4 o0, o1;
            o0.x = acc[ai][0] + bb0.x; o0.y = acc[ai][1] + bb0.y;
            o0.z = acc[ai][2] + bb0.z; o0.w = acc[ai][3] + bb0.w;
            o1.x = acc[ai][4] + bb1.x; o1.y = acc[ai][5] + bb1.y;
            o1.z = acc[ai][6] + bb1.z; o1.w = acc[ai][7] + bb1.w;
            *(float4*)(C + (size_t)row * N + c0) = o0;
            *(float4*)(C + (size_t)row * N + c1) = o1;
        }
}

// ---------------------------------------------------------------------------
// Q projection at the last position only. (unchanged)
// ---------------------------------------------------------------------------
__global__ __launch_bounds__(256) void qlast_kernel(
    const float* __restrict__ h1, const float* __restrict__ wq,
    const float* __restrict__ bq, float* __restrict__ qout)
{
    const int b = blockIdx.x;
    const int t = threadIdx.x;
    __shared__ __align__(16) float hs[HID];
    hs[t] = h1[((size_t)b * SEQ + (SEQ - 1)) * HID + t];
    __syncthreads();
    const float4* wr = (const float4*)(wq + (size_t)t * HID);
    float acc = 0.0f;
#pragma unroll
    for (int k = 0; k < 64; k++) {
        const float4 wv = wr[k];
        const float4 hv = ((const float4*)hs)[k];
        acc += wv.x*hv.x + wv.y*hv.y + wv.z*hv.z + wv.w*hv.w;
    }
    qout[b * HID + t] = acc + bq[t];
}

// ---------------------------------------------------------------------------
// Decode attention at query S-1 with multiplicative decay on scores. (unchanged)
// ---------------------------------------------------------------------------
__global__ __launch_bounds__(256) void attn_kernel(
    const float* __restrict__ Kb, const float* __restrict__ Vb,
    const float* __restrict__ q, float* __restrict__ attn)
{
    const int b = blockIdx.x >> 2;
    const int h = blockIdx.x & 3;
    const int tid = threadIdx.x;

    __shared__ __align__(16) float qs[64];
    __shared__ float sc[SEQ];
    __shared__ float red[256];
    __shared__ float part[4][64];

    if (tid < 64) qs[tid] = q[b * HID + h * 64 + tid];
    __syncthreads();

    const float LN095 = -0.051293294387550533f;  // ln(0.95)
    for (int k = tid; k < SEQ; k += 256) {
        const float4* kr = (const float4*)(Kb + ((size_t)b * SEQ + k) * HID + h * 64);
        float acc = 0.0f;
#pragma unroll
        for (int d = 0; d < 16; d++) {
            const float4 kv = kr[d];
            const float4 qv = ((const float4*)qs)[d];
            acc += kv.x*qv.x + kv.y*qv.y + kv.z*qv.z + kv.w*qv.w;
        }
        const float dec = __expf(LN095 * (float)(SEQ - 1 - k));
        sc[k] = acc * 0.125f * dec;
    }
    __syncthreads();

    float m = -INFINITY;
    for (int k = tid; k < SEQ; k += 256) m = fmaxf(m, sc[k]);
    red[tid] = m;
    for (int off = 128; off > 0; off >>= 1) {
        __syncthreads();
        if (tid < off) red[tid] = fmaxf(red[tid], red[tid + off]);
    }
    __syncthreads();
    const float mx = red[0];

    float local = 0.0f;
    for (int k = tid; k < SEQ; k += 256) {
        const float p = expf(sc[k] - mx);
        sc[k] = p;
        local += p;
    }
    __syncthreads();
    red[tid] = local;
    for (int off = 128; off > 0; off >>= 1) {
        __syncthreads();
        if (tid < off) red[tid] += red[tid + off];
    }
    __syncthreads();
    const float total = red[0];

    const int chunk = tid >> 6;
    const int d = tid & 63;
    float acc = 0.0f;
    const int k0 = chunk * (SEQ / 4), k1 = (chunk + 1) * (SEQ / 4);
    for (int k = k0; k < k1; k++)
        acc += sc[k] * Vb[((size_t)b * SEQ + k) * HID + h * 64 + d];
    part[chunk][d] = acc;
    __syncthreads();
    if (tid < 64) {
        const float r = (part[0][tid] + part[1][tid]) + (part[2][tid] + part[3][tid]);
        attn[b * HID + h * 64 + tid] = r / total;
    }
}

// ---------------------------------------------------------------------------
// Head: context = attn @ wo^T + bo ; mean/log_var heads (5 each). (unchanged)
// ---------------------------------------------------------------------------
__global__ __launch_bounds__(256) void head_kernel(
    const float* __restrict__ attn, const float* __restrict__ wo,
    const float* __restrict__ bo, const float* __restrict__ w_mean,
    const float* __restrict__ b_mean, const float* __restrict__ w_var,
    const float* __restrict__ b_var, float* __restrict__ out)
{
    const int b = blockIdx.x;
    const int t = threadIdx.x;
    __shared__ __align__(16) float av[HID];
    __shared__ __align__(16) float ctx[HID];
    av[t] = attn[b * HID + t];
    __syncthreads();
    {
        const float4* wr = (const float4*)(wo + (size_t)t * HID);
        float acc = 0.0f;
#pragma unroll
        for (int k = 0; k < 64; k++) {
            const float4 wv = wr[k];
            const float4 hv = ((const float4*)av)[k];
            acc += wv.x*hv.x + wv.y*hv.y + wv.z*hv.z + wv.w*hv.w;
        }
        ctx[t] = acc + bo[t];
    }
    __syncthreads();
    if (t < 5) {
        const float4* wr = (const float4*)(w_mean + (size_t)t * HID);
        float acc = 0.0f;
#pragma unroll
        for (int k = 0; k < 64; k++) {
            const float4 wv = wr[k];
            const float4 hv = ((const float4*)ctx)[k];
            acc += wv.x*hv.x + wv.y*hv.y + wv.z*hv.z + wv.w*hv.w;
        }
        out[b * 5 + t] = acc + b_mean[t];
    } else if (t >= 8 && t < 13) {
        const int m = t - 8;
        const float4* wr = (const float4*)(w_var + (size_t)m * HID);
        float acc = 0.0f;
#pragma unroll
        for (int k = 0; k < 64; k++) {
            const float4 wv = wr[k];
            const float4 hv = ((const float4*)ctx)[k];
            acc += wv.x*hv.x + wv.y*hv.y + wv.z*hv.z + wv.w*hv.w;
        }
        out[BATCH * 5 + b * 5 + m] = acc + b_var[m];
    }
}

// ---------------------------------------------------------------------------
extern "C" void kernel_launch(void* const* d_in, const int* in_sizes, int n_in,
                              void* d_out, int out_size, void* d_ws, size_t ws_size,
                              hipStream_t stream) {
    const float* x      = (const float*)d_in[0];
    const float* w_ih0  = (const float*)d_in[1];
    const float* w_hh0  = (const float*)d_in[2];
    const float* b_ih0  = (const float*)d_in[3];
    const float* b_hh0  = (const float*)d_in[4];
    const float* w_ih1  = (const float*)d_in[5];
    const float* w_hh1  = (const float*)d_in[6];
    const float* b_ih1  = (const float*)d_in[7];
    const float* b_hh1  = (const float*)d_in[8];
    const float* wq     = (const float*)d_in[9];
    const float* bq     = (const float*)d_in[10];
    const float* wk     = (const float*)d_in[11];
    const float* bk     = (const float*)d_in[12];
    const float* wvv    = (const float*)d_in[13];
    const float* bv     = (const float*)d_in[14];
    const float* wo     = (const float*)d_in[15];
    const float* bo     = (const float*)d_in[16];
    const float* w_mean = (const float*)d_in[17];
    const float* b_mean = (const float*)d_in[18];
    const float* w_var  = (const float*)d_in[19];
    const float* b_var  = (const float*)d_in[20];
    float* out = (float*)d_out;

    // ws layout (bytes), ~50.3 MB peak:
    //  [0, 16M)            hbuf  (plain h1; LSTM writes, KV/qlast read)
    //  [16M, 48M)          xp16  (f16-pair layer-0 input proj)  -> Kbuf|Vbuf after
    //  [48M, 48M+256K)     h0r   (32-deep tagged packed-h0 ring) -> qbuf|abuf after
    //  [48M+256K, +2M)     xpr   (32-deep tagged f32 xp ring)
    //  [52690944, +128B)   progs (L1prog[8], Pprog[8])
    char* wsb = (char*)d_ws;
    float* hbuf = (float*)wsb;
    u32*  xp16  = (u32*)(wsb + 16777216);
    u64*  h0r   = (u64*)(wsb + 50331648);
    u64*  xpr   = (u64*)(wsb + 50593792);
    u64*  progs = (u64*)(wsb + 52690944);
    float* Kbuf = (float*)(wsb + 16777216);
    float* Vbuf = (float*)(wsb + 33554432);
    float* qbuf = (float*)(wsb + 50331648);
    float* abuf = (float*)(wsb + 50331648 + 8192);

    static bool attr_done = false;
    if (!attr_done) {
        hipFuncSetAttribute(reinterpret_cast<const void*>(lstm_fused),
                            hipFuncAttributeMaxDynamicSharedMemorySize, 102400);
        attr_done = true;
    }

    // 1. layer-0 input projection (f16 pairs, biases folded)
    xproj_kernel<<<1024, 256, 0, stream>>>(x, w_ih0, b_ih0, b_hh0, xp16);
    // 2. fused single-CU-per-stage pipelined 2-layer LSTM
    //    (dyn smem 100KB: 96KB weight chunks + 4KB ring)
    lstm_fused<<<24, 512, 102400, stream>>>(xp16, w_hh0, w_ih1, b_ih1, b_hh1, w_hh1,
                                            h0r, xpr, progs, hbuf);
    // 3. K and V projections (one launch)
    gemm_kv<<<dim3(128, 2, 2), 256, 0, stream>>>(hbuf, wk, bk, wvv, bv, Kbuf, Vbuf, 16384, 256, 256);
    // 4. Q at last position
    qlast_kernel<<<BATCH, 256, 0, stream>>>(hbuf, wq, bq, qbuf);
    // 5. decode attention with decay
    attn_kernel<<<BATCH * 4, 256, 0, stream>>>(Kbuf, Vbuf, qbuf, abuf);
    // 6. output proj + gaussian head
    head_kernel<<<BATCH, 256, 0, stream>>>(abuf, wo, bo, w_mean, b_mean, w_var, b_var, out);
}

// Round 9
// 3672.543 us; speedup vs baseline: 1.6312x; 1.2853x over previous
//
#include <hip/hip_runtime.h>
#include <math.h>

#define BATCH 8
#define SEQ   2048
#define IN    8
#define HID   256
#define G4    1024   // 4*HID
#define XPR_R 64     // xp ring depth (steps)

typedef unsigned long long u64;
typedef unsigned int u32;

// ---------------------------------------------------------------------------
// R17: recovery + targeted fix on the PROVEN 3591us kernel (prev session).
// Session R10-R16 (single-CU f16 family) established: step ~= DS + VALU with
// near-zero overlap at 2 waves/SIMD + ~240 live regs -> family floor ~4200cy
// > the LLC-exchange design's 4000cy. Reverting to the 96-block design.
// The one session-proven lever applied here: __launch_bounds__(512,2) capped
// arch VGPRs at 128 -> the 128 pinned weight floats NEVER stayed resident
// (VGPR_Count=104, R9) -> 256KB/block/step re-streamed from L2 (~1700cy).
// amdgpu_waves_per_eu(2,2) (verified effective in R12: SGPR delta + 192-word
// residency) unlocks the 256-unified budget so pin_f4 actually holds
// (~128 arch + overflow in AGPR, allocator-scheduled reads).
// ---------------------------------------------------------------------------

__device__ __forceinline__ float sigmoidf_(float x) { return 1.0f / (1.0f + __expf(-x)); }
__device__ __forceinline__ float tanhf_(float x) { return 1.0f - 2.0f / (__expf(2.0f * x) + 1.0f); }
// padded LDS index for h: +4 words per 32 -> 8 distinct bank groups, conflict-free
__device__ __forceinline__ int hpad(int k) { return k + 4 * (k >> 5); }

// LDS-only barrier (R5: vmcnt-drain removal neutral but harmless; keep).
__device__ __forceinline__ void light_barrier() {
    __asm__ volatile("s_waitcnt lgkmcnt(0)\n\ts_barrier" ::: "memory");
}

// Sum over the 8 lanes {base..base+7} (lane bits 0..2) via VALU DPP (off the DS pipe).
__device__ __forceinline__ float dpp_add8(float v) {
    int x;
    x = __builtin_amdgcn_update_dpp(0, __float_as_int(v), 0xB1, 0xF, 0xF, false);  // quad_perm xor1
    v += __int_as_float(x);
    x = __builtin_amdgcn_update_dpp(0, __float_as_int(v), 0x4E, 0xF, 0xF, false);  // quad_perm xor2
    v += __int_as_float(x);
    x = __builtin_amdgcn_update_dpp(0, __float_as_int(v), 0x141, 0xF, 0xF, false); // row_half_mirror
    v += __int_as_float(x);
    return v;
}

// Tagged u64 word {tag<<32 | f32 bits}: payload inside the atomic word ->
// RELAXED store/load at agent scope (R3 win; R7 swap neutral; R8 hybrid
// regressed — reverted to the R5 form).
__device__ __forceinline__ float poll_tag(const u64* p, u32 tag) {
    u64 v;
    do { v = __hip_atomic_load(p, __ATOMIC_RELAXED, __HIP_MEMORY_SCOPE_AGENT); }
    while ((u32)(v >> 32) != tag);
    return __uint_as_float((u32)v);
}
__device__ __forceinline__ void pub_tag(u64* p, u32 tag, float x) {
    __hip_atomic_store(p, ((u64)tag << 32) | (u64)__float_as_uint(x),
                       __ATOMIC_RELAXED, __HIP_MEMORY_SCOPE_AGENT);
}

// R9/R17: pin loaded values into registers. With waves_per_eu(2,2) the
// unified budget is 256/lane, so the 128 weight floats + ~60 working fit
// (allocator backs overflow with AGPRs + its own scheduled reads). Under the
// old __launch_bounds__(512,2) 128-cap this pin could not hold (R9:
// VGPR_Count=104 -> 256 KB/block/step re-streamed from L2).
__device__ __forceinline__ void pin_f4(float4& v) {
    __asm__ volatile("" : "+v"(v.x), "+v"(v.y), "+v"(v.z), "+v"(v.w));
}

__device__ __forceinline__ void matvec8(const float4 (&w4)[4][8], const float* hrow, int ks,
                                        float& a0, float& a1, float& a2, float& a3) {
    a0 = a1 = a2 = a3 = 0.0f;
#pragma unroll
    for (int i = 0; i < 8; i++) {
        const float4 h4 = *(const float4*)(&hrow[36 * ks + 4 * i]);  // 8-lane broadcast
        a0 += w4[0][i].x*h4.x + w4[0][i].y*h4.y + w4[0][i].z*h4.z + w4[0][i].w*h4.w;
        a1 += w4[1][i].x*h4.x + w4[1][i].y*h4.y + w4[1][i].z*h4.z + w4[1][i].w*h4.w;
        a2 += w4[2][i].x*h4.x + w4[2][i].y*h4.y + w4[2][i].z*h4.z + w4[2][i].w*h4.w;
        a3 += w4[3][i].x*h4.x + w4[3][i].y*h4.y + w4[3][i].z*h4.z + w4[3][i].w*h4.w;
    }
}

// ---------------------------------------------------------------------------
// Fused pipelined 2-layer LSTM (R5 structure, 3591us proven). Grid = 96 x 512:
//   bid&7 = batch b, role = bid>>3: 0-3 L0 q; 4-7 P p; 8-11 L1 q.
// L0 -> h0 tagged write-once stream; P -> xp ring (64 steps, back-pressure
// from L1's parity ring); L1 -> parity ring + plain hbuf.
// Thread (rg=t>>3, ks=t&7) holds 4 rows x 32-col weight slice in 128 VGPRs
// (pinned — effective now via waves_per_eu(2,2), see pin_f4).
// ---------------------------------------------------------------------------
__global__
__attribute__((amdgpu_flat_work_group_size(512, 512)))
__attribute__((amdgpu_waves_per_eu(2, 2)))
void lstm_fused(
    const float* __restrict__ x,
    const float* __restrict__ w_ih0, const float* __restrict__ w_hh0,
    const float* __restrict__ b_ih0, const float* __restrict__ b_hh0,
    const float* __restrict__ w_ih1, const float* __restrict__ w_hh1,
    const float* __restrict__ b_ih1, const float* __restrict__ b_hh1,
    u64* __restrict__ h0s,    // [8][2048][256] tagged write-once
    u64* __restrict__ xpr,    // [8][64][1024]  tagged ring
    u64* __restrict__ h1r,    // [2][8][256]    tagged parity ring
    float* __restrict__ hbuf) // [8][2048][256] plain h1
{
    const int bid = blockIdx.x;
    const int b    = bid & 7;
    const int role = bid >> 3;
    const int grp  = role >> 2;   // 0 L0, 1 P, 2 L1
    const int q    = role & 3;
    const int t    = threadIdx.x;
    const int ks   = t & 7;
    const int rg   = t >> 3;
    const int wv   = t >> 6;
    const int lane = t & 63;
    const bool isg = (ks == 0);

    __shared__ float h_lds[2][288];
    __shared__ float xbuf[2][256];   // L1: xp values, [gate j][unit] (conflict-free)

    u64* h0b = h0s + (size_t)b * SEQ * HID;
    u64* xpb = xpr + (size_t)b * XPR_R * G4;

    for (int i = t; i < 576; i += 512) ((float*)h_lds)[i] = 0.0f;
    __syncthreads();

    if (grp == 0) {
        // ================= L0: layer-0 recurrence, input proj fused =========
        float4 w4[4][8];
#pragma unroll
        for (int j = 0; j < 4; j++) {
            const float4* wr = (const float4*)(w_hh0 + (size_t)(256*j + 64*q + rg) * HID + ks * 32);
#pragma unroll
            for (int i = 0; i < 8; i++) { w4[j][i] = wr[i]; pin_f4(w4[j][i]); }
        }
        float4 wi[4][2]; float bs4[4];
#pragma unroll
        for (int j = 0; j < 4; j++) {
            const int G = 256*j + 64*q + rg;
            wi[j][0] = *(const float4*)(w_ih0 + (size_t)G * IN);
            wi[j][1] = *(const float4*)(w_ih0 + (size_t)G * IN + 4);
            bs4[j] = b_ih0[G] + b_hh0[G];
        }
        const float* xb = x + (size_t)b * SEQ * IN;
        float c = 0.0f;
        float xv0 = 0, xv1 = 0, xv2 = 0, xv3 = 0;
        if (isg) {
            const float4 xa = *(const float4*)(xb);
            const float4 xc = *(const float4*)(xb + 4);
            xv0 = bs4[0] + wi[0][0].x*xa.x + wi[0][0].y*xa.y + wi[0][0].z*xa.z + wi[0][0].w*xa.w
                         + wi[0][1].x*xc.x + wi[0][1].y*xc.y + wi[0][1].z*xc.z + wi[0][1].w*xc.w;
            xv1 = bs4[1] + wi[1][0].x*xa.x + wi[1][0].y*xa.y + wi[1][0].z*xa.z + wi[1][0].w*xa.w
                         + wi[1][1].x*xc.x + wi[1][1].y*xc.y + wi[1][1].z*xc.z + wi[1][1].w*xc.w;
            xv2 = bs4[2] + wi[2][0].x*xa.x + wi[2][0].y*xa.y + wi[2][0].z*xa.z + wi[2][0].w*xa.w
                         + wi[2][1].x*xc.x + wi[2][1].y*xc.y + wi[2][1].z*xc.z + wi[2][1].w*xc.w;
            xv3 = bs4[3] + wi[3][0].x*xa.x + wi[3][0].y*xa.y + wi[3][0].z*xa.z + wi[3][0].w*xa.w
                         + wi[3][1].x*xc.x + wi[3][1].y*xc.y + wi[3][1].z*xc.z + wi[3][1].w*xc.w;
        }

        for (int s = 0; s < SEQ; s++) {
            const int cur = s & 1, nxt = cur ^ 1;
            float xn0 = 0, xn1 = 0, xn2 = 0, xn3 = 0;
            if (isg && s + 1 < SEQ) {
                const float4 xa = *(const float4*)(xb + (size_t)(s + 1) * IN);
                const float4 xc = *(const float4*)(xb + (size_t)(s + 1) * IN + 4);
                xn0 = bs4[0] + wi[0][0].x*xa.x + wi[0][0].y*xa.y + wi[0][0].z*xa.z + wi[0][0].w*xa.w
                             + wi[0][1].x*xc.x + wi[0][1].y*xc.y + wi[0][1].z*xc.z + wi[0][1].w*xc.w;
                xn1 = bs4[1] + wi[1][0].x*xa.x + wi[1][0].y*xa.y + wi[1][0].z*xa.z + wi[1][0].w*xa.w
                             + wi[1][1].x*xc.x + wi[1][1].y*xc.y + wi[1][1].z*xc.z + wi[1][1].w*xc.w;
                xn2 = bs4[2] + wi[2][0].x*xa.x + wi[2][0].y*xa.y + wi[2][0].z*xa.z + wi[2][0].w*xa.w
                             + wi[2][1].x*xc.x + wi[2][1].y*xc.y + wi[2][1].z*xc.z + wi[2][1].w*xc.w;
                xn3 = bs4[3] + wi[3][0].x*xa.x + wi[3][0].y*xa.y + wi[3][0].z*xa.z + wi[3][0].w*xa.w
                             + wi[3][1].x*xc.x + wi[3][1].y*xc.y + wi[3][1].z*xc.z + wi[3][1].w*xc.w;
            }
            float a0, a1, a2, a3;
            matvec8(w4, h_lds[cur], ks, a0, a1, a2, a3);
            a0 = dpp_add8(a0); a1 = dpp_add8(a1); a2 = dpp_add8(a2); a3 = dpp_add8(a3);
            const u32 tag = (u32)(s + 1);
            if (isg) {
                const float iv = sigmoidf_(a0 + xv0);
                const float fv = sigmoidf_(a1 + xv1);
                const float gv = tanhf_(a2 + xv2);
                const float ov = sigmoidf_(a3 + xv3);
                c = fv * c + iv * gv;
                const float hv = ov * tanhf_(c);
                const int u = 64*q + rg;
                pub_tag(&h0b[(size_t)s * HID + u], tag, hv);   // publish first (visibility path)
                h_lds[nxt][hpad(u)] = hv;
                xv0 = xn0; xv1 = xn1; xv2 = xn2; xv3 = xn3;
            }
            if (wv >= 1 && wv <= 3) {
                const int u = 64 * ((q + wv) & 3) + lane;
                h_lds[nxt][hpad(u)] = poll_tag(&h0b[(size_t)s * HID + u], tag);
            }
            light_barrier();
        }
    } else if (grp == 1) {
        // ================= P: xp[s] = w_ih1 @ h0[s] + biases ================
        const int p = q;
        float4 w4[4][8]; float bs4[4];
#pragma unroll
        for (int j = 0; j < 4; j++) {
            const int R = 256*p + 64*j + rg;
            const float4* wr = (const float4*)(w_ih1 + (size_t)R * HID + ks * 32);
#pragma unroll
            for (int i = 0; i < 8; i++) { w4[j][i] = wr[i]; pin_f4(w4[j][i]); }
            bs4[j] = b_ih1[R] + b_hh1[R];
        }
        if (wv >= 4) {   // pre-poll h0[0]
            const int u = 64 * (wv - 4) + lane;
            h_lds[0][hpad(u)] = poll_tag(&h0b[u], 1u);
        }
        __syncthreads();

        for (int s = 0; s < SEQ; s++) {
            const int cur = s & 1, nxt = cur ^ 1;
            float a0, a1, a2, a3;
            matvec8(w4, h_lds[cur], ks, a0, a1, a2, a3);
            a0 = dpp_add8(a0); a1 = dpp_add8(a1); a2 = dpp_add8(a2); a3 = dpp_add8(a3);
            const u32 tag = (u32)(s + 1);
            if (isg) {
                // ring back-pressure: slot s%64 reusable once L1 passed s-64
                if (s >= XPR_R) {
                    const u32 need = (u32)(s - (XPR_R - 1));
                    const u64* bp = h1r + ((size_t)(need & 1u) * 8 + b) * HID + (64*p + rg);
                    u32 tt;
                    do { tt = (u32)(__hip_atomic_load(bp, __ATOMIC_RELAXED, __HIP_MEMORY_SCOPE_AGENT) >> 32); }
                    while (!(tt >= need && tt <= 2048u));
                }
                u64* slot = xpb + (size_t)(s & (XPR_R - 1)) * G4 + 256*p + rg;
                pub_tag(slot +   0, tag, a0 + bs4[0]);
                pub_tag(slot +  64, tag, a1 + bs4[1]);
                pub_tag(slot + 128, tag, a2 + bs4[2]);
                pub_tag(slot + 192, tag, a3 + bs4[3]);
            }
            if (wv >= 4 && s + 1 < SEQ) {   // prefetch h0[s+1]
                const int u = 64 * (wv - 4) + lane;
                h_lds[nxt][hpad(u)] = poll_tag(&h0b[(size_t)(s + 1) * HID + u], tag + 1u);
            }
            light_barrier();
        }
    } else {
        // ================= L1: layer-1 recurrence =========================
        float4 w4[4][8];
#pragma unroll
        for (int j = 0; j < 4; j++) {
            const float4* wr = (const float4*)(w_hh1 + (size_t)(256*j + 64*q + rg) * HID + ks * 32);
#pragma unroll
            for (int i = 0; i < 8; i++) { w4[j][i] = wr[i]; pin_f4(w4[j][i]); }
        }
        float* ho = hbuf + (size_t)b * SEQ * HID;
        if (wv >= 4) {   // pre-poll xp[0]
            const int j = wv - 4;
            xbuf[0][64*j + lane] = poll_tag(&xpb[256*j + 64*q + lane], 1u);
        }
        __syncthreads();

        float c = 0.0f;
        for (int s = 0; s < SEQ; s++) {
            const int cur = s & 1, nxt = cur ^ 1;
            float a0, a1, a2, a3;
            matvec8(w4, h_lds[cur], ks, a0, a1, a2, a3);
            a0 = dpp_add8(a0); a1 = dpp_add8(a1); a2 = dpp_add8(a2); a3 = dpp_add8(a3);
            const u32 tag = (u32)(s + 1);
            if (isg) {
                const float xq0 = xbuf[cur][rg];
                const float xq1 = xbuf[cur][64 + rg];
                const float xq2 = xbuf[cur][128 + rg];
                const float xq3 = xbuf[cur][192 + rg];
                const float iv = sigmoidf_(a0 + xq0);
                const float fv = sigmoidf_(a1 + xq1);
                const float gv = tanhf_(a2 + xq2);
                const float ov = sigmoidf_(a3 + xq3);
                c = fv * c + iv * gv;
                const float hv = ov * tanhf_(c);
                const int u = 64*q + rg;
                pub_tag(&h1r[((size_t)(tag & 1u) * 8 + b) * HID + u], tag, hv);  // publish first
                h_lds[nxt][hpad(u)] = hv;
                ho[(size_t)s * HID + u] = hv;
            }
            if (wv >= 1 && wv <= 3) {   // peer exchange (parity ring, lockstep)
                const int u = 64 * ((q + wv) & 3) + lane;
                h_lds[nxt][hpad(u)] = poll_tag(&h1r[((size_t)(tag & 1u) * 8 + b) * HID + u], tag);
            }
            if (wv >= 4 && s + 1 < SEQ) {   // prefetch xp[s+1]
                const int j = wv - 4;
                xbuf[nxt][64*j + lane] =
                    poll_tag(&xpb[(size_t)((s + 1) & (XPR_R - 1)) * G4 + 256*j + 64*q + lane], tag + 1u);
            }
            light_barrier();
        }
    }
}

// ---------------------------------------------------------------------------
// K and V projections in one launch (blockIdx.z selects). NT GEMM,
// 128x128x16 tiles, 256 threads, 8x8 micro-tile.
// ---------------------------------------------------------------------------
__global__ __launch_bounds__(256) void gemm_kv(
    const float* __restrict__ A,
    const float* __restrict__ Wk, const float* __restrict__ bk,
    const float* __restrict__ Wv, const float* __restrict__ bv,
    float* __restrict__ Ck, float* __restrict__ Cv, int M, int N, int K)
{
    const float* W    = blockIdx.z ? Wv : Wk;
    const float* bias = blockIdx.z ? bv : bk;
    float*       C    = blockIdx.z ? Cv : Ck;

    __shared__ float As[16][132];
    __shared__ float Bs[16][132];
    const int tid = threadIdx.x;
    const int tx = tid & 15;
    const int ty = tid >> 4;
    const int bm = blockIdx.x * 128;
    const int bn = blockIdx.y * 128;
    const int lrow = tid >> 1;
    const int lk = (tid & 1) * 8;

    float acc[8][8] = {};

    for (int k0 = 0; k0 < K; k0 += 16) {
        const float* ap = A + (size_t)(bm + lrow) * K + k0 + lk;
        const float* wp = W + (size_t)(bn + lrow) * K + k0 + lk;
        const float4 a0 = *(const float4*)ap;
        const float4 a1 = *(const float4*)(ap + 4);
        const float4 w0 = *(const float4*)wp;
        const float4 w1 = *(const float4*)(wp + 4);
        __syncthreads();
        As[lk+0][lrow] = a0.x; As[lk+1][lrow] = a0.y; As[lk+2][lrow] = a0.z; As[lk+3][lrow] = a0.w;
        As[lk+4][lrow] = a1.x; As[lk+5][lrow] = a1.y; As[lk+6][lrow] = a1.z; As[lk+7][lrow] = a1.w;
        Bs[lk+0][lrow] = w0.x; Bs[lk+1][lrow] = w0.y; Bs[lk+2][lrow] = w0.z; Bs[lk+3][lrow] = w0.w;
        Bs[lk+4][lrow] = w1.x; Bs[lk+5][lrow] = w1.y; Bs[lk+6][lrow] = w1.z; Bs[lk+7][lrow] = w1.w;
        __syncthreads();
#pragma unroll
        for (int k = 0; k < 16; k++) {
            const float4 av0 = *(const float4*)(&As[k][ty * 4]);
            const float4 av1 = *(const float4*)(&As[k][64 + ty * 4]);
            const float4 bv0 = *(const float4*)(&Bs[k][tx * 4]);
            const float4 bv1 = *(const float4*)(&Bs[k][64 + tx * 4]);
            const float ar[8] = {av0.x, av0.y, av0.z, av0.w, av1.x, av1.y, av1.z, av1.w};
            const float br[8] = {bv0.x, bv0.y, bv0.z, bv0.w, bv1.x, bv1.y, bv1.z, bv1.w};
#pragma unroll
            for (int i = 0; i < 8; i++)
#pragma unroll
                for (int j = 0; j < 8; j++) acc[i][j] += ar[i] * br[j];
        }
    }

    const int c0 = bn + tx * 4, c1 = bn + 64 + tx * 4;
    const float4 bb0 = *(const float4*)(bias + c0);
    const float4 bb1 = *(const float4*)(bias + c1);
#pragma unroll
    for (int ih = 0; ih < 2; ih++)
#pragma unroll
        for (int i = 0; i < 4; i++) {
            const int row = bm + ih * 64 + ty * 4 + i;
            const int ai = ih * 4 + i;
            float4 o0, o1;
            o0.x = acc[ai][0] + bb0.x; o0.y = acc[ai][1] + bb0.y;
            o0.z = acc[ai][2] + bb0.z; o0.w = acc[ai][3] + bb0.w;
            o1.x = acc[ai][4] + bb1.x; o1.y = acc[ai][5] + bb1.y;
            o1.z = acc[ai][6] + bb1.z; o1.w = acc[ai][7] + bb1.w;
            *(float4*)(C + (size_t)row * N + c0) = o0;
            *(float4*)(C + (size_t)row * N + c1) = o1;
        }
}

// ---------------------------------------------------------------------------
// Q projection at the last position only.
// ---------------------------------------------------------------------------
__global__ __launch_bounds__(256) void qlast_kernel(
    const float* __restrict__ h1, const float* __restrict__ wq,
    const float* __restrict__ bq, float* __restrict__ qout)
{
    const int b = blockIdx.x;
    const int t = threadIdx.x;
    __shared__ __align__(16) float hs[HID];
    hs[t] = h1[((size_t)b * SEQ + (SEQ - 1)) * HID + t];
    __syncthreads();
    const float4* wr = (const float4*)(wq + (size_t)t * HID);
    float acc = 0.0f;
#pragma unroll
    for (int k = 0; k < 64; k++) {
        const float4 wv = wr[k];
        const float4 hv = ((const float4*)hs)[k];
        acc += wv.x*hv.x + wv.y*hv.y + wv.z*hv.z + wv.w*hv.w;
    }
    qout[b * HID + t] = acc + bq[t];
}

// ---------------------------------------------------------------------------
// Decode attention at query S-1 with multiplicative decay on scores.
// ---------------------------------------------------------------------------
__global__ __launch_bounds__(256) void attn_kernel(
    const float* __restrict__ Kb, const float* __restrict__ Vb,
    const float* __restrict__ q, float* __restrict__ attn)
{
    const int b = blockIdx.x >> 2;
    const int h = blockIdx.x & 3;
    const int tid = threadIdx.x;

    __shared__ __align__(16) float qs[64];
    __shared__ float sc[SEQ];
    __shared__ float red[256];
    __shared__ float part[4][64];

    if (tid < 64) qs[tid] = q[b * HID + h * 64 + tid];
    __syncthreads();

    const float LN095 = -0.051293294387550533f;  // ln(0.95)
    for (int k = tid; k < SEQ; k += 256) {
        const float4* kr = (const float4*)(Kb + ((size_t)b * SEQ + k) * HID + h * 64);
        float acc = 0.0f;
#pragma unroll
        for (int d = 0; d < 16; d++) {
            const float4 kv = kr[d];
            const float4 qv = ((const float4*)qs)[d];
            acc += kv.x*qv.x + kv.y*qv.y + kv.z*qv.z + kv.w*qv.w;
        }
        const float dec = __expf(LN095 * (float)(SEQ - 1 - k));
        sc[k] = acc * 0.125f * dec;
    }
    __syncthreads();

    float m = -INFINITY;
    for (int k = tid; k < SEQ; k += 256) m = fmaxf(m, sc[k]);
    red[tid] = m;
    for (int off = 128; off > 0; off >>= 1) {
        __syncthreads();
        if (tid < off) red[tid] = fmaxf(red[tid], red[tid + off]);
    }
    __syncthreads();
    const float mx = red[0];

    float local = 0.0f;
    for (int k = tid; k < SEQ; k += 256) {
        const float p = expf(sc[k] - mx);
        sc[k] = p;
        local += p;
    }
    __syncthreads();
    red[tid] = local;
    for (int off = 128; off > 0; off >>= 1) {
        __syncthreads();
        if (tid < off) red[tid] += red[tid + off];
    }
    __syncthreads();
    const float total = red[0];

    const int chunk = tid >> 6;
    const int d = tid & 63;
    float acc = 0.0f;
    const int k0 = chunk * (SEQ / 4), k1 = (chunk + 1) * (SEQ / 4);
    for (int k = k0; k < k1; k++)
        acc += sc[k] * Vb[((size_t)b * SEQ + k) * HID + h * 64 + d];
    part[chunk][d] = acc;
    __syncthreads();
    if (tid < 64) {
        const float r = (part[0][tid] + part[1][tid]) + (part[2][tid] + part[3][tid]);
        attn[b * HID + h * 64 + tid] = r / total;
    }
}

// ---------------------------------------------------------------------------
// Head: context = attn @ wo^T + bo ; mean/log_var heads (5 each).
// ---------------------------------------------------------------------------
__global__ __launch_bounds__(256) void head_kernel(
    const float* __restrict__ attn, const float* __restrict__ wo,
    const float* __restrict__ bo, const float* __restrict__ w_mean,
    const float* __restrict__ b_mean, const float* __restrict__ w_var,
    const float* __restrict__ b_var, float* __restrict__ out)
{
    const int b = blockIdx.x;
    const int t = threadIdx.x;
    __shared__ __align__(16) float av[HID];
    __shared__ __align__(16) float ctx[HID];
    av[t] = attn[b * HID + t];
    __syncthreads();
    {
        const float4* wr = (const float4*)(wo + (size_t)t * HID);
        float acc = 0.0f;
#pragma unroll
        for (int k = 0; k < 64; k++) {
            const float4 wv = wr[k];
            const float4 hv = ((const float4*)av)[k];
            acc += wv.x*hv.x + wv.y*hv.y + wv.z*hv.z + wv.w*hv.w;
        }
        ctx[t] = acc + bo[t];
    }
    __syncthreads();
    if (t < 5) {
        const float4* wr = (const float4*)(w_mean + (size_t)t * HID);
        float acc = 0.0f;
#pragma unroll
        for (int k = 0; k < 64; k++) {
            const float4 wv = wr[k];
            const float4 hv = ((const float4*)ctx)[k];
            acc += wv.x*hv.x + wv.y*hv.y + wv.z*hv.z + wv.w*hv.w;
        }
        out[b * 5 + t] = acc + b_mean[t];
    } else if (t >= 8 && t < 13) {
        const int m = t - 8;
        const float4* wr = (const float4*)(w_var + (size_t)m * HID);
        float acc = 0.0f;
#pragma unroll
        for (int k = 0; k < 64; k++) {
            const float4 wv = wr[k];
            const float4 hv = ((const float4*)ctx)[k];
            acc += wv.x*hv.x + wv.y*hv.y + wv.z*hv.z + wv.w*hv.w;
        }
        out[BATCH * 5 + b * 5 + m] = acc + b_var[m];
    }
}

// ---------------------------------------------------------------------------
extern "C" void kernel_launch(void* const* d_in, const int* in_sizes, int n_in,
                              void* d_out, int out_size, void* d_ws, size_t ws_size,
                              hipStream_t stream) {
    const float* x      = (const float*)d_in[0];
    const float* w_ih0  = (const float*)d_in[1];
    const float* w_hh0  = (const float*)d_in[2];
    const float* b_ih0  = (const float*)d_in[3];
    const float* b_hh0  = (const float*)d_in[4];
    const float* w_ih1  = (const float*)d_in[5];
    const float* w_hh1  = (const float*)d_in[6];
    const float* b_ih1  = (const float*)d_in[7];
    const float* b_hh1  = (const float*)d_in[8];
    const float* wq     = (const float*)d_in[9];
    const float* bq     = (const float*)d_in[10];
    const float* wk     = (const float*)d_in[11];
    const float* bk     = (const float*)d_in[12];
    const float* wvv    = (const float*)d_in[13];
    const float* bv     = (const float*)d_in[14];
    const float* wo     = (const float*)d_in[15];
    const float* bo     = (const float*)d_in[16];
    const float* w_mean = (const float*)d_in[17];
    const float* b_mean = (const float*)d_in[18];
    const float* w_var  = (const float*)d_in[19];
    const float* b_var  = (const float*)d_in[20];
    float* out = (float*)d_out;

    // ws layout (bytes), ~54 MB peak:
    //  [0, 32M)        h0s tagged stream (fused) -> Kbuf|Vbuf after
    //  [32M, 36M)      xpr ring (fused)          -> qbuf|abuf after
    //  [36M, 36M+32K)  h1r parity ring (fused)
    //  [36M+32K, +16M) hbuf: plain h1 (fused writes; KV/qlast read)
    char* wsb = (char*)d_ws;
    u64*  h0s  = (u64*)(wsb);
    u64*  xpr  = (u64*)(wsb + 33554432);
    u64*  h1r  = (u64*)(wsb + 37748736);
    float* hbuf = (float*)(wsb + 37781504);
    float* Kbuf = (float*)(wsb);
    float* Vbuf = (float*)(wsb + 16777216);
    float* qbuf = (float*)(wsb + 33554432);
    float* abuf = (float*)(wsb + 33554432 + 8192);

    // 1. fused pipelined 2-layer LSTM (h1 -> hbuf)
    lstm_fused<<<96, 512, 0, stream>>>(x, w_ih0, w_hh0, b_ih0, b_hh0,
                                       w_ih1, w_hh1, b_ih1, b_hh1,
                                       h0s, xpr, h1r, hbuf);
    // 2. K and V projections (one launch)
    gemm_kv<<<dim3(128, 2, 2), 256, 0, stream>>>(hbuf, wk, bk, wvv, bv, Kbuf, Vbuf, 16384, 256, 256);
    // 3. Q at last position
    qlast_kernel<<<BATCH, 256, 0, stream>>>(hbuf, wq, bq, qbuf);
    // 4. decode attention with decay
    attn_kernel<<<BATCH * 4, 256, 0, stream>>>(Kbuf, Vbuf, qbuf, abuf);
    // 5. output proj + gaussian head
    head_kernel<<<BATCH, 256, 0, stream>>>(abuf, wo, bo, w_mean, b_mean, w_var, b_var, out);
}

// Round 13
// 3527.560 us; speedup vs baseline: 1.6983x; 1.0411x over previous
//
#include <hip/hip_runtime.h>
#include <math.h>

#define BATCH 8
#define SEQ   2048
#define IN    8
#define HID   256
#define G4    1024   // 4*HID
#define XPR_R 64     // xp ring depth (steps)

typedef unsigned long long u64;
typedef unsigned int u32;
typedef _Float16 f16;

// ---------------------------------------------------------------------------
// R19 (resubmit; GPU-timeout round, fix re-verified) = R18 + DPP direction
// fix. R18 FAILED absmax 3.66e-3 (> 8.25e-4): producer pack used 0x118
// row_shr:8 (lane i reads i-8; rg=0 read invalid -> 0, rg=2 read h[1] not
// h[3]) -> all 32 odd-position h values in each L0/L1 block's OWN chunk were
// wrong in the recurrent matvec. Correct op is row_shl:8 = 0x108 (lane i
// reads i+8 = partner rg+1; writers {0,16,32,48} read {8,24,40,56}, all
// within 16-lane DPP rows). Contained corruption (h0 LLC stream publishes
// exact f32 BEFORE packing, so P saw clean data) explains the modest error.
// Poller path (quad_perm xor1) was correct. f16 precision itself is fine:
// R10-R16 family with identical f16 weights+h measured 2.4e-4.
// Design (R18): f16-dot2 matvec inside the PROVEN 96-block LLC-exchange
// structure. R17 measured VALU ~2000cy (51% of active: 128 FMA + ~128
// accvgpr_read) + ~2000cy LLC exchange wait ~= 4030cy/step. Packed-f16
// v_dot2_f32_f16: per-thread weights 128 f32 -> 64 packed words = 64 VGPRs,
// FULLY arch-resident (no AGPR reads), FMA count halved. h packed at the
// source (producers dpp row_shl:8, pollers dpp xor1); LLC streams stay
// exact f32. DS traffic halves (4 b128/thread/step); +4 words/16 pad -> the
// 8 broadcast streams tile all 32 banks, conflict-free.
// Model: VALU ~450cy + exchange ~2000-2400cy -> step ~2500-2900cy vs 4030.
// ---------------------------------------------------------------------------

__device__ __forceinline__ float sigmoidf_(float x) { return 1.0f / (1.0f + __expf(-x)); }
__device__ __forceinline__ float tanhf_(float x) { return 1.0f - 2.0f / (__expf(2.0f * x) + 1.0f); }

// packed-word LDS index: +4 words per 16 -> uint4 stays 16B-aligned and the
// 8 ks-streams hit banks 20ks+4i mod 32 = all-distinct -> conflict-free.
__device__ __forceinline__ int hword(int p) { return p + 4 * (p >> 4); }

// f32 -> packed 2xf16 (RNE — RTZ bias would accumulate over 2048 steps).
__device__ __forceinline__ u32 pk2h(float a, float b) {
    unsigned short ua = __builtin_bit_cast(unsigned short, (f16)a);
    unsigned short ub = __builtin_bit_cast(unsigned short, (f16)b);
    return (u32)ua | ((u32)ub << 16);
}

// LDS-only barrier (R5: vmcnt-drain removal neutral but harmless; keep).
__device__ __forceinline__ void light_barrier() {
    __asm__ volatile("s_waitcnt lgkmcnt(0)\n\ts_barrier" ::: "memory");
}

// Sum over the 8 lanes {base..base+7} (lane bits 0..2) via VALU DPP (off the DS pipe).
__device__ __forceinline__ float dpp_add8(float v) {
    int x;
    x = __builtin_amdgcn_update_dpp(0, __float_as_int(v), 0xB1, 0xF, 0xF, false);  // quad_perm xor1
    v += __int_as_float(x);
    x = __builtin_amdgcn_update_dpp(0, __float_as_int(v), 0x4E, 0xF, 0xF, false);  // quad_perm xor2
    v += __int_as_float(x);
    x = __builtin_amdgcn_update_dpp(0, __float_as_int(v), 0x141, 0xF, 0xF, false); // row_half_mirror
    v += __int_as_float(x);
    return v;
}

// Tagged u64 word {tag<<32 | f32 bits}: payload inside the atomic word ->
// RELAXED store/load at agent scope (proven pattern).
__device__ __forceinline__ float poll_tag(const u64* p, u32 tag) {
    u64 v;
    do { v = __hip_atomic_load(p, __ATOMIC_RELAXED, __HIP_MEMORY_SCOPE_AGENT); }
    while ((u32)(v >> 32) != tag);
    return __uint_as_float((u32)v);
}
__device__ __forceinline__ void pub_tag(u64* p, u32 tag, float x) {
    __hip_atomic_store(p, ((u64)tag << 32) | (u64)__float_as_uint(x),
                       __ATOMIC_RELAXED, __HIP_MEMORY_SCOPE_AGENT);
}

// pin packed weight words into registers across the step loop.
__device__ __forceinline__ void pin1(u32& v) { __asm__ volatile("" : "+v"(v)); }

// packed-f16 dot2 with f32 accumulator (full-rate VALU, 2 FMA/instr)
#define DOT2(ACC, W, H) __asm__("v_dot2_f32_f16 %0, %1, %2, %0" : "+v"(ACC) : "v"(W), "v"(H))

// ---------------------------------------------------------------------------
// Packed matvec: thread (rg, ks) x 4 gate rows over cols [32ks, 32ks+32) =
// packed words [16ks, 16ks+16). 4 broadcast ds_read_b128 per thread.
// ---------------------------------------------------------------------------
__device__ __forceinline__ void matvec8p(const u32 (&wp)[4][16], const u32* hl, int ks,
                                         float& a0, float& a1, float& a2, float& a3) {
    a0 = a1 = a2 = a3 = 0.0f;
#pragma unroll
    for (int i = 0; i < 4; i++) {
        const uint4 h4 = *(const uint4*)(hl + 20 * ks + 4 * i);  // 8-lane broadcast, bank-clean
        DOT2(a0, wp[0][4*i+0], h4.x); DOT2(a0, wp[0][4*i+1], h4.y);
        DOT2(a0, wp[0][4*i+2], h4.z); DOT2(a0, wp[0][4*i+3], h4.w);
        DOT2(a1, wp[1][4*i+0], h4.x); DOT2(a1, wp[1][4*i+1], h4.y);
        DOT2(a1, wp[1][4*i+2], h4.z); DOT2(a1, wp[1][4*i+3], h4.w);
        DOT2(a2, wp[2][4*i+0], h4.x); DOT2(a2, wp[2][4*i+1], h4.y);
        DOT2(a2, wp[2][4*i+2], h4.z); DOT2(a2, wp[2][4*i+3], h4.w);
        DOT2(a3, wp[3][4*i+0], h4.x); DOT2(a3, wp[3][4*i+1], h4.y);
        DOT2(a3, wp[3][4*i+2], h4.z); DOT2(a3, wp[3][4*i+3], h4.w);
    }
}

// load 4 rows x 32 cols f32, pack to 16 words/row, pin.
__device__ __forceinline__ void load_w_packed(const float* __restrict__ W, int r0, int r1,
                                              int r2, int r3, int colbase, u32 (&wp)[4][16]) {
    const int rows[4] = {r0, r1, r2, r3};
#pragma unroll
    for (int j = 0; j < 4; j++) {
        const float4* wr = (const float4*)(W + (size_t)rows[j] * HID + colbase);
#pragma unroll
        for (int i = 0; i < 8; i++) {
            const float4 f = wr[i];
            wp[j][2*i]   = pk2h(f.x, f.y);
            wp[j][2*i+1] = pk2h(f.z, f.w);
        }
    }
#pragma unroll
    for (int j = 0; j < 4; j++)
#pragma unroll
        for (int k = 0; k < 16; k++) pin1(wp[j][k]);
}

// ---------------------------------------------------------------------------
// Fused pipelined 2-layer LSTM (R5 96-block structure + f16 dot2 matvec).
// Grid = 96 x 512: bid&7 = batch b, role = bid>>3: 0-3 L0 q; 4-7 P p; 8-11 L1 q.
// L0 -> h0 tagged write-once stream; P -> xp ring (64 steps, back-pressure
// from L1's parity ring); L1 -> parity ring + plain hbuf. LLC streams carry
// exact f32; h is packed to f16 pairs at LDS-write time.
// ---------------------------------------------------------------------------
__global__
__attribute__((amdgpu_flat_work_group_size(512, 512)))
__attribute__((amdgpu_waves_per_eu(2, 2)))
void lstm_fused(
    const float* __restrict__ x,
    const float* __restrict__ w_ih0, const float* __restrict__ w_hh0,
    const float* __restrict__ b_ih0, const float* __restrict__ b_hh0,
    const float* __restrict__ w_ih1, const float* __restrict__ w_hh1,
    const float* __restrict__ b_ih1, const float* __restrict__ b_hh1,
    u64* __restrict__ h0s,    // [8][2048][256] tagged write-once
    u64* __restrict__ xpr,    // [8][64][1024]  tagged ring
    u64* __restrict__ h1r,    // [2][8][256]    tagged parity ring
    float* __restrict__ hbuf) // [8][2048][256] plain h1
{
    const int bid = blockIdx.x;
    const int b    = bid & 7;
    const int role = bid >> 3;
    const int grp  = role >> 2;   // 0 L0, 1 P, 2 L1
    const int q    = role & 3;
    const int t    = threadIdx.x;
    const int ks   = t & 7;
    const int rg   = t >> 3;
    const int wv   = t >> 6;
    const int lane = t & 63;
    const bool isg = (ks == 0);

    __shared__ __align__(16) u32 h_pk[2][160];   // packed h (128 words + pad)
    __shared__ float xbuf[2][256];               // L1: xp values (f32)

    u64* h0b = h0s + (size_t)b * SEQ * HID;
    u64* xpb = xpr + (size_t)b * XPR_R * G4;

    for (int i = t; i < 320; i += 512) ((u32*)h_pk)[i] = 0u;
    __syncthreads();

    if (grp == 0) {
        // ================= L0: layer-0 recurrence, input proj fused =========
        u32 wp[4][16];
        load_w_packed(w_hh0, 64*q + rg, 256 + 64*q + rg, 512 + 64*q + rg, 768 + 64*q + rg,
                      ks * 32, wp);
        float4 wi[4][2]; float bs4[4];
#pragma unroll
        for (int j = 0; j < 4; j++) {
            const int G = 256*j + 64*q + rg;
            wi[j][0] = *(const float4*)(w_ih0 + (size_t)G * IN);
            wi[j][1] = *(const float4*)(w_ih0 + (size_t)G * IN + 4);
            bs4[j] = b_ih0[G] + b_hh0[G];
        }
        const float* xb = x + (size_t)b * SEQ * IN;
        float c = 0.0f;
        float xv0 = 0, xv1 = 0, xv2 = 0, xv3 = 0;
        if (isg) {
            const float4 xa = *(const float4*)(xb);
            const float4 xc = *(const float4*)(xb + 4);
            xv0 = bs4[0] + wi[0][0].x*xa.x + wi[0][0].y*xa.y + wi[0][0].z*xa.z + wi[0][0].w*xa.w
                         + wi[0][1].x*xc.x + wi[0][1].y*xc.y + wi[0][1].z*xc.z + wi[0][1].w*xc.w;
            xv1 = bs4[1] + wi[1][0].x*xa.x + wi[1][0].y*xa.y + wi[1][0].z*xa.z + wi[1][0].w*xa.w
                         + wi[1][1].x*xc.x + wi[1][1].y*xc.y + wi[1][1].z*xc.z + wi[1][1].w*xc.w;
            xv2 = bs4[2] + wi[2][0].x*xa.x + wi[2][0].y*xa.y + wi[2][0].z*xa.z + wi[2][0].w*xa.w
                         + wi[2][1].x*xc.x + wi[2][1].y*xc.y + wi[2][1].z*xc.z + wi[2][1].w*xc.w;
            xv3 = bs4[3] + wi[3][0].x*xa.x + wi[3][0].y*xa.y + wi[3][0].z*xa.z + wi[3][0].w*xa.w
                         + wi[3][1].x*xc.x + wi[3][1].y*xc.y + wi[3][1].z*xc.z + wi[3][1].w*xc.w;
        }

        for (int s = 0; s < SEQ; s++) {
            const int cur = s & 1, nxt = cur ^ 1;
            float xn0 = 0, xn1 = 0, xn2 = 0, xn3 = 0;
            if (isg && s + 1 < SEQ) {
                const float4 xa = *(const float4*)(xb + (size_t)(s + 1) * IN);
                const float4 xc = *(const float4*)(xb + (size_t)(s + 1) * IN + 4);
                xn0 = bs4[0] + wi[0][0].x*xa.x + wi[0][0].y*xa.y + wi[0][0].z*xa.z + wi[0][0].w*xa.w
                             + wi[0][1].x*xc.x + wi[0][1].y*xc.y + wi[0][1].z*xc.z + wi[0][1].w*xc.w;
                xn1 = bs4[1] + wi[1][0].x*xa.x + wi[1][0].y*xa.y + wi[1][0].z*xa.z + wi[1][0].w*xa.w
                             + wi[1][1].x*xc.x + wi[1][1].y*xc.y + wi[1][1].z*xc.z + wi[1][1].w*xc.w;
                xn2 = bs4[2] + wi[2][0].x*xa.x + wi[2][0].y*xa.y + wi[2][0].z*xa.z + wi[2][0].w*xa.w
                             + wi[2][1].x*xc.x + wi[2][1].y*xc.y + wi[2][1].z*xc.z + wi[2][1].w*xc.w;
                xn3 = bs4[3] + wi[3][0].x*xa.x + wi[3][0].y*xa.y + wi[3][0].z*xa.z + wi[3][0].w*xa.w
                             + wi[3][1].x*xc.x + wi[3][1].y*xc.y + wi[3][1].z*xc.z + wi[3][1].w*xc.w;
            }
            float a0, a1, a2, a3;
            matvec8p(wp, h_pk[cur], ks, a0, a1, a2, a3);
            a0 = dpp_add8(a0); a1 = dpp_add8(a1); a2 = dpp_add8(a2); a3 = dpp_add8(a3);
            const u32 tag = (u32)(s + 1);
            if (isg) {
                const float iv = sigmoidf_(a0 + xv0);
                const float fv = sigmoidf_(a1 + xv1);
                const float gv = tanhf_(a2 + xv2);
                const float ov = sigmoidf_(a3 + xv3);
                c = fv * c + iv * gv;
                const float hv = ov * tanhf_(c);
                const int u = 64*q + rg;
                pub_tag(&h0b[(size_t)s * HID + u], tag, hv);   // publish first (f32, exact)
                // pack pair (rg even, rg+1): partner is lane+8 -> row_shl:8 (0x108)
                const int nb = __builtin_amdgcn_update_dpp(0, __float_as_int(hv), 0x108, 0xF, 0xF, false);
                if ((rg & 1) == 0)
                    h_pk[nxt][hword(32*q + (rg >> 1))] = pk2h(hv, __int_as_float(nb));
                xv0 = xn0; xv1 = xn1; xv2 = xn2; xv3 = xn3;
            }
            if (wv >= 1 && wv <= 3) {
                const int u = 64 * ((q + wv) & 3) + lane;
                const float pv = poll_tag(&h0b[(size_t)s * HID + u], tag);
                const int nb = __builtin_amdgcn_update_dpp(0, __float_as_int(pv), 0xB1, 0xF, 0xF, false);
                if ((lane & 1) == 0)
                    h_pk[nxt][hword(32*((q + wv) & 3) + (lane >> 1))] = pk2h(pv, __int_as_float(nb));
            }
            light_barrier();
        }
    } else if (grp == 1) {
        // ================= P: xp[s] = w_ih1 @ h0[s] + biases ================
        const int p = q;
        u32 wp[4][16]; float bs4[4];
        load_w_packed(w_ih1, 256*p + rg, 256*p + 64 + rg, 256*p + 128 + rg, 256*p + 192 + rg,
                      ks * 32, wp);
#pragma unroll
        for (int j = 0; j < 4; j++) {
            const int R = 256*p + 64*j + rg;
            bs4[j] = b_ih1[R] + b_hh1[R];
        }
        if (wv >= 4) {   // pre-poll h0[0], packed
            const int u = 64 * (wv - 4) + lane;
            const float pv = poll_tag(&h0b[u], 1u);
            const int nb = __builtin_amdgcn_update_dpp(0, __float_as_int(pv), 0xB1, 0xF, 0xF, false);
            if ((lane & 1) == 0)
                h_pk[0][hword(32*(wv - 4) + (lane >> 1))] = pk2h(pv, __int_as_float(nb));
        }
        __syncthreads();

        for (int s = 0; s < SEQ; s++) {
            const int cur = s & 1, nxt = cur ^ 1;
            float a0, a1, a2, a3;
            matvec8p(wp, h_pk[cur], ks, a0, a1, a2, a3);
            a0 = dpp_add8(a0); a1 = dpp_add8(a1); a2 = dpp_add8(a2); a3 = dpp_add8(a3);
            const u32 tag = (u32)(s + 1);
            if (isg) {
                // ring back-pressure: slot s%64 reusable once L1 passed s-64
                if (s >= XPR_R) {
                    const u32 need = (u32)(s - (XPR_R - 1));
                    const u64* bp = h1r + ((size_t)(need & 1u) * 8 + b) * HID + (64*p + rg);
                    u32 tt;
                    do { tt = (u32)(__hip_atomic_load(bp, __ATOMIC_RELAXED, __HIP_MEMORY_SCOPE_AGENT) >> 32); }
                    while (!(tt >= need && tt <= 2048u));
                }
                u64* slot = xpb + (size_t)(s & (XPR_R - 1)) * G4 + 256*p + rg;
                pub_tag(slot +   0, tag, a0 + bs4[0]);
                pub_tag(slot +  64, tag, a1 + bs4[1]);
                pub_tag(slot + 128, tag, a2 + bs4[2]);
                pub_tag(slot + 192, tag, a3 + bs4[3]);
            }
            if (wv >= 4 && s + 1 < SEQ) {   // prefetch h0[s+1], packed
                const int u = 64 * (wv - 4) + lane;
                const float pv = poll_tag(&h0b[(size_t)(s + 1) * HID + u], tag + 1u);
                const int nb = __builtin_amdgcn_update_dpp(0, __float_as_int(pv), 0xB1, 0xF, 0xF, false);
                if ((lane & 1) == 0)
                    h_pk[nxt][hword(32*(wv - 4) + (lane >> 1))] = pk2h(pv, __int_as_float(nb));
            }
            light_barrier();
        }
    } else {
        // ================= L1: layer-1 recurrence =========================
        u32 wp[4][16];
        load_w_packed(w_hh1, 64*q + rg, 256 + 64*q + rg, 512 + 64*q + rg, 768 + 64*q + rg,
                      ks * 32, wp);
        float* ho = hbuf + (size_t)b * SEQ * HID;
        if (wv >= 4) {   // pre-poll xp[0] (f32)
            const int j = wv - 4;
            xbuf[0][64*j + lane] = poll_tag(&xpb[256*j + 64*q + lane], 1u);
        }
        __syncthreads();

        float c = 0.0f;
        for (int s = 0; s < SEQ; s++) {
            const int cur = s & 1, nxt = cur ^ 1;
            float a0, a1, a2, a3;
            matvec8p(wp, h_pk[cur], ks, a0, a1, a2, a3);
            a0 = dpp_add8(a0); a1 = dpp_add8(a1); a2 = dpp_add8(a2); a3 = dpp_add8(a3);
            const u32 tag = (u32)(s + 1);
            if (isg) {
                const float xq0 = xbuf[cur][rg];
                const float xq1 = xbuf[cur][64 + rg];
                const float xq2 = xbuf[cur][128 + rg];
                const float xq3 = xbuf[cur][192 + rg];
                const float iv = sigmoidf_(a0 + xq0);
                const float fv = sigmoidf_(a1 + xq1);
                const float gv = tanhf_(a2 + xq2);
                const float ov = sigmoidf_(a3 + xq3);
                c = fv * c + iv * gv;
                const float hv = ov * tanhf_(c);
                const int u = 64*q + rg;
                pub_tag(&h1r[((size_t)(tag & 1u) * 8 + b) * HID + u], tag, hv);  // publish first
                // pack pair: partner is lane+8 -> row_shl:8 (0x108)
                const int nb = __builtin_amdgcn_update_dpp(0, __float_as_int(hv), 0x108, 0xF, 0xF, false);
                if ((rg & 1) == 0)
                    h_pk[nxt][hword(32*q + (rg >> 1))] = pk2h(hv, __int_as_float(nb));
                ho[(size_t)s * HID + u] = hv;
            }
            if (wv >= 1 && wv <= 3) {   // peer exchange (parity ring, lockstep)
                const int u = 64 * ((q + wv) & 3) + lane;
                const float pv = poll_tag(&h1r[((size_t)(tag & 1u) * 8 + b) * HID + u], tag);
                const int nb = __builtin_amdgcn_update_dpp(0, __float_as_int(pv), 0xB1, 0xF, 0xF, false);
                if ((lane & 1) == 0)
                    h_pk[nxt][hword(32*((q + wv) & 3) + (lane >> 1))] = pk2h(pv, __int_as_float(nb));
            }
            if (wv >= 4 && s + 1 < SEQ) {   // prefetch xp[s+1] (f32)
                const int j = wv - 4;
                xbuf[nxt][64*j + lane] =
                    poll_tag(&xpb[(size_t)((s + 1) & (XPR_R - 1)) * G4 + 256*j + 64*q + lane], tag + 1u);
            }
            light_barrier();
        }
    }
}

// ---------------------------------------------------------------------------
// K and V projections in one launch (blockIdx.z selects). NT GEMM,
// 128x128x16 tiles, 256 threads, 8x8 micro-tile. (unchanged)
// ---------------------------------------------------------------------------
__global__ __launch_bounds__(256) void gemm_kv(
    const float* __restrict__ A,
    const float* __restrict__ Wk, const float* __restrict__ bk,
    const float* __restrict__ Wv, const float* __restrict__ bv,
    float* __restrict__ Ck, float* __restrict__ Cv, int M, int N, int K)
{
    const float* W    = blockIdx.z ? Wv : Wk;
    const float* bias = blockIdx.z ? bv : bk;
    float*       C    = blockIdx.z ? Cv : Ck;

    __shared__ float As[16][132];
    __shared__ float Bs[16][132];
    const int tid = threadIdx.x;
    const int tx = tid & 15;
    const int ty = tid >> 4;
    const int bm = blockIdx.x * 128;
    const int bn = blockIdx.y * 128;
    const int lrow = tid >> 1;
    const int lk = (tid & 1) * 8;

    float acc[8][8] = {};

    for (int k0 = 0; k0 < K; k0 += 16) {
        const float* ap = A + (size_t)(bm + lrow) * K + k0 + lk;
        const float* wp = W + (size_t)(bn + lrow) * K + k0 + lk;
        const float4 a0 = *(const float4*)ap;
        const float4 a1 = *(const float4*)(ap + 4);
        const float4 w0 = *(const float4*)wp;
        const float4 w1 = *(const float4*)(wp + 4);
        __syncthreads();
        As[lk+0][lrow] = a0.x; As[lk+1][lrow] = a0.y; As[lk+2][lrow] = a0.z; As[lk+3][lrow] = a0.w;
        As[lk+4][lrow] = a1.x; As[lk+5][lrow] = a1.y; As[lk+6][lrow] = a1.z; As[lk+7][lrow] = a1.w;
        Bs[lk+0][lrow] = w0.x; Bs[lk+1][lrow] = w0.y; Bs[lk+2][lrow] = w0.z; Bs[lk+3][lrow] = w0.w;
        Bs[lk+4][lrow] = w1.x; Bs[lk+5][lrow] = w1.y; Bs[lk+6][lrow] = w1.z; Bs[lk+7][lrow] = w1.w;
        __syncthreads();
#pragma unroll
        for (int k = 0; k < 16; k++) {
            const float4 av0 = *(const float4*)(&As[k][ty * 4]);
            const float4 av1 = *(const float4*)(&As[k][64 + ty * 4]);
            const float4 bv0 = *(const float4*)(&Bs[k][tx * 4]);
            const float4 bv1 = *(const float4*)(&Bs[k][64 + tx * 4]);
            const float ar[8] = {av0.x, av0.y, av0.z, av0.w, av1.x, av1.y, av1.z, av1.w};
            const float br[8] = {bv0.x, bv0.y, bv0.z, bv0.w, bv1.x, bv1.y, bv1.z, bv1.w};
#pragma unroll
            for (int i = 0; i < 8; i++)
#pragma unroll
                for (int j = 0; j < 8; j++) acc[i][j] += ar[i] * br[j];
        }
    }

    const int c0 = bn + tx * 4, c1 = bn + 64 + tx * 4;
    const float4 bb0 = *(const float4*)(bias + c0);
    const float4 bb1 = *(const float4*)(bias + c1);
#pragma unroll
    for (int ih = 0; ih < 2; ih++)
#pragma unroll
        for (int i = 0; i < 4; i++) {
            const int row = bm + ih * 64 + ty * 4 + i;
            const int ai = ih * 4 + i;
            float4 o0, o1;
            o0.x = acc[ai][0] + bb0.x; o0.y = acc[ai][1] + bb0.y;
            o0.z = acc[ai][2] + bb0.z; o0.w = acc[ai][3] + bb0.w;
            o1.x = acc[ai][4] + bb1.x; o1.y = acc[ai][5] + bb1.y;
            o1.z = acc[ai][6] + bb1.z; o1.w = acc[ai][7] + bb1.w;
            *(float4*)(C + (size_t)row * N + c0) = o0;
            *(float4*)(C + (size_t)row * N + c1) = o1;
        }
}

// ---------------------------------------------------------------------------
// Q projection at the last position only. (unchanged)
// ---------------------------------------------------------------------------
__global__ __launch_bounds__(256) void qlast_kernel(
    const float* __restrict__ h1, const float* __restrict__ wq,
    const float* __restrict__ bq, float* __restrict__ qout)
{
    const int b = blockIdx.x;
    const int t = threadIdx.x;
    __shared__ __align__(16) float hs[HID];
    hs[t] = h1[((size_t)b * SEQ + (SEQ - 1)) * HID + t];
    __syncthreads();
    const float4* wr = (const float4*)(wq + (size_t)t * HID);
    float acc = 0.0f;
#pragma unroll
    for (int k = 0; k < 64; k++) {
        const float4 wv = wr[k];
        const float4 hv = ((const float4*)hs)[k];
        acc += wv.x*hv.x + wv.y*hv.y + wv.z*hv.z + wv.w*hv.w;
    }
    qout[b * HID + t] = acc + bq[t];
}

// ---------------------------------------------------------------------------
// Decode attention at query S-1 with multiplicative decay on scores. (unchanged)
// ---------------------------------------------------------------------------
__global__ __launch_bounds__(256) void attn_kernel(
    const float* __restrict__ Kb, const float* __restrict__ Vb,
    const float* __restrict__ q, float* __restrict__ attn)
{
    const int b = blockIdx.x >> 2;
    const int h = blockIdx.x & 3;
    const int tid = threadIdx.x;

    __shared__ __align__(16) float qs[64];
    __shared__ float sc[SEQ];
    __shared__ float red[256];
    __shared__ float part[4][64];

    if (tid < 64) qs[tid] = q[b * HID + h * 64 + tid];
    __syncthreads();

    const float LN095 = -0.051293294387550533f;  // ln(0.95)
    for (int k = tid; k < SEQ; k += 256) {
        const float4* kr = (const float4*)(Kb + ((size_t)b * SEQ + k) * HID + h * 64);
        float acc = 0.0f;
#pragma unroll
        for (int d = 0; d < 16; d++) {
            const float4 kv = kr[d];
            const float4 qv = ((const float4*)qs)[d];
            acc += kv.x*qv.x + kv.y*qv.y + kv.z*qv.z + kv.w*qv.w;
        }
        const float dec = __expf(LN095 * (float)(SEQ - 1 - k));
        sc[k] = acc * 0.125f * dec;
    }
    __syncthreads();

    float m = -INFINITY;
    for (int k = tid; k < SEQ; k += 256) m = fmaxf(m, sc[k]);
    red[tid] = m;
    for (int off = 128; off > 0; off >>= 1) {
        __syncthreads();
        if (tid < off) red[tid] = fmaxf(red[tid], red[tid + off]);
    }
    __syncthreads();
    const float mx = red[0];

    float local = 0.0f;
    for (int k = tid; k < SEQ; k += 256) {
        const float p = expf(sc[k] - mx);
        sc[k] = p;
        local += p;
    }
    __syncthreads();
    red[tid] = local;
    for (int off = 128; off > 0; off >>= 1) {
        __syncthreads();
        if (tid < off) red[tid] += red[tid + off];
    }
    __syncthreads();
    const float total = red[0];

    const int chunk = tid >> 6;
    const int d = tid & 63;
    float acc = 0.0f;
    const int k0 = chunk * (SEQ / 4), k1 = (chunk + 1) * (SEQ / 4);
    for (int k = k0; k < k1; k++)
        acc += sc[k] * Vb[((size_t)b * SEQ + k) * HID + h * 64 + d];
    part[chunk][d] = acc;
    __syncthreads();
    if (tid < 64) {
        const float r = (part[0][tid] + part[1][tid]) + (part[2][tid] + part[3][tid]);
        attn[b * HID + h * 64 + tid] = r / total;
    }
}

// ---------------------------------------------------------------------------
// Head: context = attn @ wo^T + bo ; mean/log_var heads (5 each). (unchanged)
// ---------------------------------------------------------------------------
__global__ __launch_bounds__(256) void head_kernel(
    const float* __restrict__ attn, const float* __restrict__ wo,
    const float* __restrict__ bo, const float* __restrict__ w_mean,
    const float* __restrict__ b_mean, const float* __restrict__ w_var,
    const float* __restrict__ b_var, float* __restrict__ out)
{
    const int b = blockIdx.x;
    const int t = threadIdx.x;
    __shared__ __align__(16) float av[HID];
    __shared__ __align__(16) float ctx[HID];
    av[t] = attn[b * HID + t];
    __syncthreads();
    {
        const float4* wr = (const float4*)(wo + (size_t)t * HID);
        float acc = 0.0f;
#pragma unroll
        for (int k = 0; k < 64; k++) {
            const float4 wv = wr[k];
            const float4 hv = ((const float4*)av)[k];
            acc += wv.x*hv.x + wv.y*hv.y + wv.z*hv.z + wv.w*hv.w;
        }
        ctx[t] = acc + bo[t];
    }
    __syncthreads();
    if (t < 5) {
        const float4* wr = (const float4*)(w_mean + (size_t)t * HID);
        float acc = 0.0f;
#pragma unroll
        for (int k = 0; k < 64; k++) {
            const float4 wv = wr[k];
            const float4 hv = ((const float4*)ctx)[k];
            acc += wv.x*hv.x + wv.y*hv.y + wv.z*hv.z + wv.w*hv.w;
        }
        out[b * 5 + t] = acc + b_mean[t];
    } else if (t >= 8 && t < 13) {
        const int m = t - 8;
        const float4* wr = (const float4*)(w_var + (size_t)m * HID);
        float acc = 0.0f;
#pragma unroll
        for (int k = 0; k < 64; k++) {
            const float4 wv = wr[k];
            const float4 hv = ((const float4*)ctx)[k];
            acc += wv.x*hv.x + wv.y*hv.y + wv.z*hv.z + wv.w*hv.w;
        }
        out[BATCH * 5 + b * 5 + m] = acc + b_var[m];
    }
}

// ---------------------------------------------------------------------------
extern "C" void kernel_launch(void* const* d_in, const int* in_sizes, int n_in,
                              void* d_out, int out_size, void* d_ws, size_t ws_size,
                              hipStream_t stream) {
    const float* x      = (const float*)d_in[0];
    const float* w_ih0  = (const float*)d_in[1];
    const float* w_hh0  = (const float*)d_in[2];
    const float* b_ih0  = (const float*)d_in[3];
    const float* b_hh0  = (const float*)d_in[4];
    const float* w_ih1  = (const float*)d_in[5];
    const float* w_hh1  = (const float*)d_in[6];
    const float* b_ih1  = (const float*)d_in[7];
    const float* b_hh1  = (const float*)d_in[8];
    const float* wq     = (const float*)d_in[9];
    const float* bq     = (const float*)d_in[10];
    const float* wk     = (const float*)d_in[11];
    const float* bk     = (const float*)d_in[12];
    const float* wvv    = (const float*)d_in[13];
    const float* bv     = (const float*)d_in[14];
    const float* wo     = (const float*)d_in[15];
    const float* bo     = (const float*)d_in[16];
    const float* w_mean = (const float*)d_in[17];
    const float* b_mean = (const float*)d_in[18];
    const float* w_var  = (const float*)d_in[19];
    const float* b_var  = (const float*)d_in[20];
    float* out = (float*)d_out;

    // ws layout (bytes), ~54 MB peak:
    //  [0, 32M)        h0s tagged stream (fused) -> Kbuf|Vbuf after
    //  [32M, 36M)      xpr ring (fused)          -> qbuf|abuf after
    //  [36M, 36M+32K)  h1r parity ring (fused)
    //  [36M+32K, +16M) hbuf: plain h1 (fused writes; KV/qlast read)
    char* wsb = (char*)d_ws;
    u64*  h0s  = (u64*)(wsb);
    u64*  xpr  = (u64*)(wsb + 33554432);
    u64*  h1r  = (u64*)(wsb + 37748736);
    float* hbuf = (float*)(wsb + 37781504);
    float* Kbuf = (float*)(wsb);
    float* Vbuf = (float*)(wsb + 16777216);
    float* qbuf = (float*)(wsb + 33554432);
    float* abuf = (float*)(wsb + 33554432 + 8192);

    // 1. fused pipelined 2-layer LSTM (h1 -> hbuf)
    lstm_fused<<<96, 512, 0, stream>>>(x, w_ih0, w_hh0, b_ih0, b_hh0,
                                       w_ih1, w_hh1, b_ih1, b_hh1,
                                       h0s, xpr, h1r, hbuf);
    // 2. K and V projections (one launch)
    gemm_kv<<<dim3(128, 2, 2), 256, 0, stream>>>(hbuf, wk, bk, wvv, bv, Kbuf, Vbuf, 16384, 256, 256);
    // 3. Q at last position
    qlast_kernel<<<BATCH, 256, 0, stream>>>(hbuf, wq, bq, qbuf);
    // 4. decode attention with decay
    attn_kernel<<<BATCH * 4, 256, 0, stream>>>(Kbuf, Vbuf, qbuf, abuf);
    // 5. output proj + gaussian head
    head_kernel<<<BATCH, 256, 0, stream>>>(abuf, wo, bo, w_mean, b_mean, w_var, b_var, out);
}